// Round 8
// baseline (200.342 us; speedup 1.0000x reference)
//
#include <hip/hip_runtime.h>
#include <stdint.h>

// Match numpy reference bit-exactly on the IoU path: no fma contraction.
#pragma clang fp contract(off)

#define BF 4
#define NN 4096
#define MAXC 16
#define PL 2048   // per-label partition capacity
#define WL 32     // PL/64 words per partition row

typedef unsigned long long u64;
typedef uint32_t u32;

__device__ __forceinline__ u64 shfl64(u64 v, int src) {
  return (u64)__shfl((long long)v, src, 64);
}
__device__ __forceinline__ u64 readlane64(u64 v, int l) {
  u32 lo = (u32)__builtin_amdgcn_readlane((int)(u32)v, l);
  u32 hi = (u32)__builtin_amdgcn_readlane((int)(u32)(v >> 32), l);
  return ((u64)hi << 32) | lo;
}

// ---------------------------------------------------------------------------
// K1: per-frame stable descending sort by score — LDS radix (1 block/frame).
// 7 passes x 4 bits over hi32 bits [32..59]; top nibble pass provably
// redundant for these inputs (see r7 notes). Bit-sliced ballot ranking.
// ---------------------------------------------------------------------------
__global__ __launch_bounds__(1024) void sort_kernel(
    const float* __restrict__ scores, u64* __restrict__ keyS)
{
  __shared__ u64 keyA[NN];                  // 32 KB
  __shared__ u64 keyB[NN];                  // 32 KB
  __shared__ int cnt16[16][65];             // [bin][chunk], padded
  __shared__ int waveTot[16];
  __shared__ int waveBase[16];
  const int f = blockIdx.x, tid = threadIdx.x;
  const int wave = tid >> 6, lane = tid & 63;
  const u64 ltmask = (1ull << lane) - 1ull;

  for (int s = 0; s < 4; s++) {
    int idx = tid + 1024 * s;
    float sc = scores[f * NN + idx];
    bool valid = sc > 0.2f;                 // COND_THRES
    u32 bits = __float_as_uint(sc);
    u32 m = bits ^ ((bits >> 31) ? 0xFFFFFFFFu : 0x80000000u);
    u32 hi = valid ? ~m : 0xFFFFFFFFu;      // smaller = higher score
    keyA[idx] = ((u64)hi << 32) | (u32)idx; // idx payload = stable tie-break
  }
  __syncthreads();

  u64* src = keyA;
  u64* dst = keyB;
  for (int pass = 0; pass < 7; pass++) {
    const int shift = 32 + 4 * pass;
    u64 kreg[4]; int dreg[4], rreg[4];
    for (int s = 0; s < 4; s++) {
      const int c = wave * 4 + s;
      u64 k = src[c * 64 + lane];
      int d = (int)((k >> shift) & 15);
      u64 B0 = __ballot((d & 1) != 0);
      u64 B1 = __ballot((d & 2) != 0);
      u64 B2 = __ballot((d & 4) != 0);
      u64 B3 = __ballot((d & 8) != 0);
      u64 M = ((d & 1) ? B0 : ~B0) & ((d & 2) ? B1 : ~B1)
            & ((d & 4) ? B2 : ~B2) & ((d & 8) ? B3 : ~B3);
      rreg[s] = __popcll(M & ltmask);
      int bin = lane & 15;
      u64 Mb = ((bin & 1) ? B0 : ~B0) & ((bin & 2) ? B1 : ~B1)
             & ((bin & 4) ? B2 : ~B2) & ((bin & 8) ? B3 : ~B3);
      if (lane < 16) cnt16[bin][c] = __popcll(Mb);
      kreg[s] = k; dreg[s] = d;
    }
    __syncthreads();
    {
      int v = cnt16[wave][lane];
      int incl = v;
      for (int off2 = 1; off2 < 64; off2 <<= 1) {
        int up = __shfl_up(incl, off2, 64);
        if (lane >= off2) incl += up;
      }
      if (lane == 63) waveTot[wave] = incl;
      __syncthreads();
      if (wave == 0) {
        int tv = (lane < 16) ? waveTot[lane] : 0;
        int ts = tv;
        for (int off2 = 1; off2 < 16; off2 <<= 1) {
          int up = __shfl_up(ts, off2, 64);
          if (lane >= off2) ts += up;
        }
        if (lane < 16) waveBase[lane] = ts - tv;
      }
      __syncthreads();
      cnt16[wave][lane] = waveBase[wave] + incl - v;  // exclusive start
    }
    __syncthreads();
    for (int s = 0; s < 4; s++) {
      const int c = wave * 4 + s;
      int pos = cnt16[dreg[s]][c] + rreg[s];
      dst[pos] = kreg[s];
    }
    __syncthreads();
    u64* tmp = src; src = dst; dst = tmp;
  }
  for (int s = 0; s < 4; s++) {            // 7 passes (odd) -> result in src
    int p = tid + 1024 * s;
    keyS[f * NN + p] = src[p];
  }
}

// ---------------------------------------------------------------------------
// K2: fused per-chunk label counts + exclusive scan (1 block/frame).
// ---------------------------------------------------------------------------
__global__ __launch_bounds__(256) void countscan_kernel(
    const u64* __restrict__ keyS, const int* __restrict__ labels,
    int* __restrict__ chunkOffG, int* __restrict__ VbufL)
{
  __shared__ int cnt[64][3];
  const int f = blockIdx.x, tid = threadIdx.x;
  const int wave = tid >> 6, lane = tid & 63;
  for (int s = 0; s < 16; s++) {
    int chunk = wave * 16 + s;
    int p = chunk * 64 + lane;
    u64 kv = keyS[f * NN + p];
    bool valid = (u32)(kv >> 32) != 0xFFFFFFFFu;
    int g = (int)(kv & 0xFFFFFFFFull);
    int l = valid ? labels[f * NN + g] : 3;
    u64 B0 = __ballot((l & 1) != 0);
    u64 B1 = __ballot((l & 2) != 0);
    if (lane < 3) {
      u64 Mb = ((lane & 1) ? B0 : ~B0) & ((lane & 2) ? B1 : ~B1);
      cnt[chunk][lane] = __popcll(Mb);
    }
  }
  __syncthreads();
  if (wave == 0) {
    for (int ll = 0; ll < 3; ll++) {
      int v = cnt[lane][ll];
      int incl = v;
      for (int off2 = 1; off2 < 64; off2 <<= 1) {
        int up = __shfl_up(incl, off2, 64);
        if (lane >= off2) incl += up;
      }
      chunkOffG[(f * 64 + lane) * 3 + ll] = incl - v;
      if (lane == 63) VbufL[f * 3 + ll] = incl;
    }
  }
}

// ---------------------------------------------------------------------------
// K3 (wide): gather sorted boxes/score/label + BEV + partition scatter.
// ---------------------------------------------------------------------------
__global__ __launch_bounds__(256) void gather_kernel(
    const u64* __restrict__ keyS, const float* __restrict__ boxes,
    const float* __restrict__ scores, const int* __restrict__ labels,
    const int* __restrict__ chunkOffG,
    float* __restrict__ sboxes, float* __restrict__ sscore, float* __restrict__ slabel,
    int* __restrict__ lab_slot, int* __restrict__ loc_slot,
    int* __restrict__ pglob,
    float* __restrict__ px1, float* __restrict__ px2, float* __restrict__ py1,
    float* __restrict__ py2, float* __restrict__ parea)
{
  const int gs = blockIdx.x * 256 + threadIdx.x;
  const int f = gs >> 12, p = gs & (NN - 1);
  const int lane = threadIdx.x & 63, chunk = p >> 6;
  const u64 ltmask = (1ull << lane) - 1ull;
  u64 kv = keyS[gs];
  bool valid = (u32)(kv >> 32) != 0xFFFFFFFFu;
  int g = (int)(kv & 0xFFFFFFFFull);
  const float* bp = boxes + (size_t)(f * NN + g) * 7;
  float b0 = bp[0], b1v = bp[1], b2v = bp[2], b3 = bp[3], b4 = bp[4], b5 = bp[5], b6 = bp[6];
  int lab = labels[f * NN + g];
  const int o = f * NN + p;
  float* sb = sboxes + (size_t)o * 7;
  sb[0] = b0; sb[1] = b1v; sb[2] = b2v; sb[3] = b3; sb[4] = b4; sb[5] = b5; sb[6] = b6;
  sscore[o] = scores[f * NN + g];
  slabel[o] = (float)lab;
  int l = valid ? lab : 3;
  u64 B0 = __ballot((l & 1) != 0);
  u64 B1 = __ballot((l & 2) != 0);
  u64 M = ((l & 1) ? B0 : ~B0) & ((l & 2) ? B1 : ~B1);
  int rank = __popcll(M & ltmask);
  if (l < 3) {
    int loc = chunkOffG[(f * 64 + chunk) * 3 + l] + rank;
    int pi = (f * 3 + l) * PL + loc;
    float off = (float)l * 10000.0f;        // CLASS_OFFSET
    float cx = b0 + off, cy = b1v;
    float hx = b3 * 0.5f, hy = b4 * 0.5f;
    float x1 = cx - hx, x2 = cx + hx, y1 = cy - hy, y2 = cy + hy;
    float area = (x2 - x1) * (y2 - y1);
    pglob[pi] = p;
    px1[pi] = x1; px2[pi] = x2; py1[pi] = y1; py2[pi] = y2; parea[pi] = area;
    lab_slot[o] = l; loc_slot[o] = loc;
  } else {
    lab_slot[o] = -1; loc_slot[o] = -1;
  }
}

// ---------------------------------------------------------------------------
// Kernel B: per-partition overlap bitmask, two layouts. Early-out for
// column-words >= Vl BEFORE the 64-IoU loop (saves ~45% of wt=1 tiles).
// ---------------------------------------------------------------------------
__global__ __launch_bounds__(256) void mask_kernel(
    const float* __restrict__ px1, const float* __restrict__ px2,
    const float* __restrict__ py1, const float* __restrict__ py2,
    const float* __restrict__ parea, const int* __restrict__ pglob,
    const int* __restrict__ VbufL,
    u64* __restrict__ maskP, u64* __restrict__ maskT)
{
  __shared__ float4 cbox[1024];
  __shared__ float carea[1024];
  const int bx = blockIdx.x;                // fl*256 + rt*2 + wt
  const int fl = bx >> 8, rem = bx & 255;
  const int rt = rem >> 1, wt = rem & 1;
  const int r0 = rt * 16;
  const int Vl = VbufL[fl];
  if (r0 >= Vl) return;
  if (wt * 1024 >= Vl) return;
  const int tid = threadIdx.x;
  for (int q = tid; q < 1024; q += 256) {
    int c = fl * PL + wt * 1024 + q;
    cbox[q] = make_float4(px1[c], px2[c], py1[c], py2[c]);
    carea[q] = parea[c];
  }
  __syncthreads();
  const int row = r0 + (tid & 15);
  const int wl = tid >> 4;
  const int cw = wt * 16 + wl;
  const int nc = Vl - cw * 64;              // valid cols in this word
  if (row >= Vl || nc <= 0) return;
  const int rg = fl * PL + row;
  const float rx1 = px1[rg], rx2 = px2[rg], ry1 = py1[rg], ry2 = py2[rg], ra = parea[rg];
  u64 bits = 0;
  const int qb = wl * 64;
  for (int b = 0; b < 64; b++) {
    float4 cb = cbox[qb + b];
    float ca = carea[qb + b];
    float ix = fminf(rx2, cb.y) - fmaxf(rx1, cb.x);
    ix = fmaxf(ix, 0.0f);
    float iy = fminf(ry2, cb.w) - fmaxf(ry1, cb.z);
    iy = fmaxf(iy, 0.0f);
    float inter = ix * iy;
    float den = fmaxf((ra + ca) - inter, 1e-6f);
    float iou = inter / den;
    bits |= ((u64)(iou > 0.3f)) << b;       // IOU_THRES
  }
  if (nc < 64) bits &= (1ull << nc) - 1ull;
  const int f = fl / 3;
  const int p = pglob[fl * PL + row];
  maskP[((size_t)f * NN + p) * WL + cw] = bits;
  maskT[((size_t)fl * WL + cw) * PL + row] = bits;
}

// ---------------------------------------------------------------------------
// Kernel C: leader pass. ONE WAVE per (frame,label).
//  - TWO STATIC LDS buffers + 2x-unrolled w-loop: read/DMA buffers are
//    compile-time distinct objects -> compiler need not drain DMA (vmcnt)
//    before ds_reads of the other buffer (r7's 6360cy/iter hypothesis).
//  - DMA chunk count capped to real stream length, padded to a constant 16
//    issues (duplicate last chunk) so s_waitcnt vmcnt(16) stays immediate.
//  - Apply loop unrolled x4; v==w skipped (all alive rows of the diag block
//    provably die during the greedy).
//  - Final vmcnt(0) drain before exit (outstanding DMA at s_endpgm could
//    corrupt a successor block's LDS).
// ---------------------------------------------------------------------------
__device__ __forceinline__ void dma16(const u64* gbase, u64* lbase, int nch, int lane) {
  const char* g = (const char*)gbase;
#pragma unroll
  for (int it = 0; it < 16; it++) {
    int itc = (it < nch) ? it : (nch - 1);
    __builtin_amdgcn_global_load_lds(
        (const __attribute__((address_space(1))) unsigned int*)(g + (size_t)itc * 1024 + (size_t)lane * 16),
        (__attribute__((address_space(3))) unsigned int*)((char*)lbase + (size_t)it * 1024),
        16, 0, 0);
  }
}

__global__ __launch_bounds__(64) void nms_kernel(
    const u64* __restrict__ maskT, const int* __restrict__ VbufL,
    u64* __restrict__ leadersP)
{
  __shared__ u64 bufA[PL];                  // 16 KB
  __shared__ u64 bufB[PL];                  // 16 KB
  const int fl = blockIdx.x, lane = threadIdx.x;
  const int Vl = VbufL[fl];
  const int W = (Vl + 63) >> 6;
  const u64* mT = maskT + (size_t)fl * WL * PL;
  u64 alive = 0;
  if (lane < WL) {
    int rb = Vl - 64 * lane;
    alive = (rb >= 64) ? ~0ull : ((rb > 0) ? ((1ull << rb) - 1ull) : 0ull);
  }
  u64 myLead = 0;

#define NMS_STEP(WV, RB, DB)                                                  \
  {                                                                           \
    const int w_ = (WV);                                                      \
    int s_ = w_ + 1; if (s_ >= W) s_ = W - 1;                                 \
    int nch_ = (W - s_ + 1) >> 1; if (nch_ < 1) nch_ = 1;                     \
    dma16(mT + (size_t)s_ * PL + (size_t)64 * s_, DB, nch_, lane);            \
    asm volatile("s_waitcnt vmcnt(16)" ::: "memory");                         \
    u64 D_ = RB[lane];                                                        \
    u64 rem_ = readlane64(alive, w_);                                         \
    u64 lead_ = 0;                                                            \
    while (rem_) {                                                            \
      int b_ = __builtin_ctzll(rem_);                                         \
      lead_ |= 1ull << b_;                                                    \
      rem_ &= ~readlane64(D_, b_);                                            \
    }                                                                         \
    if (lane == w_) myLead = lead_;                                           \
    if (lead_) {                                                              \
      int v_ = w_ + 1;                                                        \
      for (; v_ + 3 < W; v_ += 4) {                                           \
        u64 a0 = RB[64 * (v_ - w_) + lane];                                   \
        u64 a1 = RB[64 * (v_ + 1 - w_) + lane];                               \
        u64 a2 = RB[64 * (v_ + 2 - w_) + lane];                               \
        u64 a3 = RB[64 * (v_ + 3 - w_) + lane];                               \
        u64 b0 = __ballot((a0 & lead_) != 0ull);                              \
        u64 b1 = __ballot((a1 & lead_) != 0ull);                              \
        u64 b2 = __ballot((a2 & lead_) != 0ull);                              \
        u64 b3 = __ballot((a3 & lead_) != 0ull);                              \
        if (lane == v_)     alive &= ~b0;                                     \
        if (lane == v_ + 1) alive &= ~b1;                                     \
        if (lane == v_ + 2) alive &= ~b2;                                     \
        if (lane == v_ + 3) alive &= ~b3;                                     \
      }                                                                       \
      for (; v_ < W; v_++) {                                                  \
        u64 a0 = RB[64 * (v_ - w_) + lane];                                   \
        u64 b0 = __ballot((a0 & lead_) != 0ull);                              \
        if (lane == v_) alive &= ~b0;                                         \
      }                                                                       \
    }                                                                         \
  }

  if (W > 0) {
    dma16(mT, bufA, (W + 1) >> 1, lane);    // prime stream 0 -> bufA
    for (int w = 0; w < W; w += 2) {
      NMS_STEP(w, bufA, bufB);
      if (w + 1 < W) NMS_STEP(w + 1, bufB, bufA);
    }
  }
  asm volatile("s_waitcnt vmcnt(0)" ::: "memory");  // drain before endpgm
#undef NMS_STEP
  if (lane < WL) leadersP[fl * WL + lane] = myLead;
}

// ---------------------------------------------------------------------------
// Kernel D: parallel cid (partition-local). One wave per slot.
// ---------------------------------------------------------------------------
__global__ __launch_bounds__(256) void cid_kernel(
    const u64* __restrict__ maskP, const u64* __restrict__ leadersP,
    const int* __restrict__ lab_slot, const int* __restrict__ loc_slot,
    const int* __restrict__ VbufL, int* __restrict__ cidP)
{
  const int g = blockIdx.x * 4 + (threadIdx.x >> 6);
  const int lane = threadIdx.x & 63;
  const int f = g >> 12, p = g & (NN - 1);
  const int l = lab_slot[f * NN + p];
  if (l < 0) return;
  const int fl = f * 3 + l;
  const int loc = loc_slot[f * NN + p];
  const int Wl = (VbufL[fl] + 63) >> 6;
  u64 L = 0, m = 0;
  if (lane < Wl) {
    L = leadersP[fl * WL + lane];
    m = maskP[((size_t)f * NN + p) * WL + lane];
  }
  const int g6 = loc >> 6, b6 = loc & 63;
  u64 pmask = (lane < g6) ? ~0ull
            : (lane == g6 ? ((b6 == 63) ? ~0ull : ((1ull << (b6 + 1)) - 1ull)) : 0ull);
  u64 v = m & L & pmask;
  u64 bl = __ballot(v != 0ull);
  int cid = -1;
  if (bl != 0ull) {
    int w = __builtin_ctzll(bl);
    u64 vw = shfl64(v, w);
    cid = w * 64 + __builtin_ctzll(vw);
  }
  if (lane == 0) cidP[fl * PL + loc] = cid;
}

// ---------------------------------------------------------------------------
// Kernel E: fused members + merge. One 64-thread block per row.
// ---------------------------------------------------------------------------
__global__ __launch_bounds__(64) void mm_kernel(
    const u64* __restrict__ maskP, const u64* __restrict__ leadersP,
    const int* __restrict__ cidP, const int* __restrict__ lab_slot,
    const int* __restrict__ loc_slot, const int* __restrict__ pglob,
    const int* __restrict__ VbufL,
    const float* __restrict__ sboxes, const float* __restrict__ sscore,
    const float* __restrict__ slabel,
    const float* __restrict__ W1, const float* __restrict__ b1,
    const float* __restrict__ W2, const float* __restrict__ b2,
    float* __restrict__ out)
{
  const int bi = blockIdx.x;
  const int f = bi >> 12, i = bi & (NN - 1);
  const int lane = threadIdx.x;
  const int o = f * NN + i;
  float* info = out + (size_t)o * 9;
  float* lead = out + (size_t)BF * NN * 9 + o;
  const int l = lab_slot[o];
  bool isLead = false;
  int loc = 0, fl = 0;
  if (l >= 0) {
    fl = f * 3 + l;
    loc = loc_slot[o];
    isLead = (leadersP[fl * WL + (loc >> 6)] >> (loc & 63)) & 1ull;
  }
  if (!isLead) {
    if (lane < 9) info[lane] = 0.0f;
    if (lane == 0) *lead = 0.0f;
    return;
  }
  __shared__ int mlist[MAXC];
  __shared__ float mb[MAXC][7];
  __shared__ float lg[MAXC];
  __shared__ float wn[MAXC];
  const u64* mrow = maskP + (size_t)o * WL;
  const int Wl = (VbufL[fl] + 63) >> 6;
  int total = 0;
  for (int w = loc >> 6; w < Wl && total < MAXC; w++) {
    u64 word = mrow[w];
    int pos = w * 64 + lane;
    bool cand = ((word >> lane) & 1ull) && (cidP[fl * PL + pos] == loc);
    u64 mbal = __ballot(cand);
    int r = __popcll(mbal & ((1ull << lane) - 1ull));
    int slot = total + r;
    if (cand && slot < MAXC) mlist[slot] = pglob[fl * PL + pos];
    total += __popcll(mbal);
  }
  const int cnt = min(total, MAXC);
  __syncthreads();
  if (lane < cnt) {
    int j = mlist[lane];
    const float* bp = sboxes + (size_t)(f * NN + j) * 7;
    for (int d = 0; d < 7; d++) mb[lane][d] = bp[d];
  }
  float w1r[7];
  for (int d = 0; d < 7; d++) w1r[d] = W1[d * 64 + lane];
  const float b1c = b1[lane], w2c = W2[lane], b2v = b2[0];
  __syncthreads();
  for (int s = 0; s < cnt; s++) {
    float t = b1c;
    for (int d = 0; d < 7; d++) t += mb[s][d] * w1r[d];
    float h = fmaxf(t, 0.0f);
    float v = h * w2c;
    for (int off2 = 32; off2 > 0; off2 >>= 1) v += __shfl_xor(v, off2, 64);
    if (lane == 0) lg[s] = v + b2v;
  }
  __syncthreads();
  float mx = -1e30f;
  for (int s = 0; s < cnt; s++) mx = fmaxf(mx, lg[s]);
  float den = 0.0f;
  for (int s = 0; s < cnt; s++) den += expf(lg[s] - mx);
  if (lane < cnt) wn[lane] = expf(lg[lane] - mx) / den;
  __syncthreads();
  float val = 0.0f;
  if (lane < 7) {
    float acc = 0.0f;
    for (int s = 0; s < cnt; s++) acc += wn[s] * mb[s][lane];
    val = acc;
    if (lane >= 3 && lane <= 5 && val <= 0.0f) val = sboxes[(size_t)o * 7 + lane];
  } else if (lane == 7) {
    val = sscore[o];
  } else if (lane == 8) {
    val = slabel[o];
  }
  if (lane < 9) info[lane] = val;
  if (lane == 0) *lead = 1.0f;
}

// ---------------------------------------------------------------------------
extern "C" void kernel_launch(void* const* d_in, const int* in_sizes, int n_in,
                              void* d_out, int out_size, void* d_ws, size_t ws_size,
                              hipStream_t stream)
{
  const float* boxes  = (const float*)d_in[0];
  const float* scores = (const float*)d_in[1];
  const int*   labels = (const int*)d_in[2];
  const float* W1     = (const float*)d_in[3];
  const float* b1     = (const float*)d_in[4];
  const float* W2     = (const float*)d_in[5];
  const float* b2     = (const float*)d_in[6];
  float* out = (float*)d_out;

  char* ws = (char*)d_ws;
  size_t off = 0;
  auto alloc = [&](size_t bytes) -> void* {
    void* p = ws + off;
    off = (off + bytes + 255) & ~(size_t)255;
    return p;
  };
  u64*   keyS    = (u64*)  alloc((size_t)BF * NN * 8);
  int*   chunkOffG=(int*)  alloc((size_t)BF * 64 * 3 * 4);
  float* sboxes  = (float*)alloc((size_t)BF * NN * 7 * 4);
  float* sscore  = (float*)alloc((size_t)BF * NN * 4);
  float* slabel  = (float*)alloc((size_t)BF * NN * 4);
  int*   lab_slot= (int*)  alloc((size_t)BF * NN * 4);
  int*   loc_slot= (int*)  alloc((size_t)BF * NN * 4);
  int*   pglob   = (int*)  alloc((size_t)BF * 3 * PL * 4);
  float* px1     = (float*)alloc((size_t)BF * 3 * PL * 4);
  float* px2     = (float*)alloc((size_t)BF * 3 * PL * 4);
  float* py1     = (float*)alloc((size_t)BF * 3 * PL * 4);
  float* py2     = (float*)alloc((size_t)BF * 3 * PL * 4);
  float* parea   = (float*)alloc((size_t)BF * 3 * PL * 4);
  int*   VbufL   = (int*)  alloc((size_t)BF * 3 * 4);
  u64*   leadersP= (u64*)  alloc((size_t)BF * 3 * WL * 8);
  int*   cidP    = (int*)  alloc((size_t)BF * 3 * PL * 4);
  u64*   maskP   = (u64*)  alloc((size_t)BF * NN * WL * 8);        // 4 MB
  u64*   maskT   = (u64*)  alloc((size_t)BF * 3 * WL * PL * 8);    // 6 MB
  (void)  alloc(32768);                     // DMA overrun slack after maskT

  sort_kernel<<<BF, 1024, 0, stream>>>(scores, keyS);
  countscan_kernel<<<BF, 256, 0, stream>>>(keyS, labels, chunkOffG, VbufL);
  gather_kernel<<<BF * NN / 256, 256, 0, stream>>>(keyS, boxes, scores, labels,
                                                   chunkOffG, sboxes, sscore,
                                                   slabel, lab_slot, loc_slot,
                                                   pglob, px1, px2, py1, py2,
                                                   parea);
  mask_kernel<<<BF * 3 * 256, 256, 0, stream>>>(px1, px2, py1, py2, parea,
                                                pglob, VbufL, maskP, maskT);
  nms_kernel<<<BF * 3, 64, 0, stream>>>(maskT, VbufL, leadersP);
  cid_kernel<<<BF * NN / 4, 256, 0, stream>>>(maskP, leadersP, lab_slot,
                                              loc_slot, VbufL, cidP);
  mm_kernel<<<BF * NN, 64, 0, stream>>>(maskP, leadersP, cidP, lab_slot,
                                        loc_slot, pglob, VbufL, sboxes,
                                        sscore, slabel, W1, b1, W2, b2, out);
}

// Round 10
// 199.185 us; speedup vs baseline: 1.0058x; 1.0058x over previous
//
#include <hip/hip_runtime.h>
#include <stdint.h>

// Match numpy reference bit-exactly on the IoU path: no fma contraction.
#pragma clang fp contract(off)

#define BF 4
#define NN 4096
#define MAXC 16
#define PL 2048   // per-label partition capacity
#define WL 32     // PL/64 words per partition row
#define WF 24     // full-LDS leader-pass capacity (Vl<=1536; +15.7 sigma)
#define TRI_CAP (64 * (WL * (WL + 1) / 2))  // per-fl packed triangle capacity (u64)

typedef unsigned long long u64;
typedef uint32_t u32;

__device__ __forceinline__ u64 shfl64(u64 v, int src) {
  return (u64)__shfl((long long)v, src, 64);
}
__device__ __forceinline__ u64 readlane64(u64 v, int l) {
  u32 lo = (u32)__builtin_amdgcn_readlane((int)(u32)v, l);
  u32 hi = (u32)__builtin_amdgcn_readlane((int)(u32)(v >> 32), l);
  return ((u64)hi << 32) | lo;
}
// Greedy NMS inside one 64-row block: D = lane's row word (diag), rem = alive
// rows of the block (uniform). Serial chain = ctz+readlane64+andn per leader.
__device__ __forceinline__ u64 greedy64(u64 D, u64 rem) {
  u64 lead = 0;
  while (rem) {
    int b = __builtin_ctzll(rem);
    lead |= 1ull << b;
    rem &= ~readlane64(D, b);
  }
  return lead;
}

// ---------------------------------------------------------------------------
// K1: per-frame stable descending sort by score — LDS radix (1 block/frame).
// 7 passes x 4 bits over hi32 bits [32..59]; top-nibble pass provably
// redundant for these inputs. Bit-sliced ballot ranking.
// ---------------------------------------------------------------------------
__global__ __launch_bounds__(1024) void sort_kernel(
    const float* __restrict__ scores, u64* __restrict__ keyS)
{
  __shared__ u64 keyA[NN];                  // 32 KB
  __shared__ u64 keyB[NN];                  // 32 KB
  __shared__ int cnt16[16][65];             // [bin][chunk], padded
  __shared__ int waveTot[16];
  __shared__ int waveBase[16];
  const int f = blockIdx.x, tid = threadIdx.x;
  const int wave = tid >> 6, lane = tid & 63;
  const u64 ltmask = (1ull << lane) - 1ull;

  for (int s = 0; s < 4; s++) {
    int idx = tid + 1024 * s;
    float sc = scores[f * NN + idx];
    bool valid = sc > 0.2f;                 // COND_THRES
    u32 bits = __float_as_uint(sc);
    u32 m = bits ^ ((bits >> 31) ? 0xFFFFFFFFu : 0x80000000u);
    u32 hi = valid ? ~m : 0xFFFFFFFFu;      // smaller = higher score
    keyA[idx] = ((u64)hi << 32) | (u32)idx; // idx payload = stable tie-break
  }
  __syncthreads();

  u64* src = keyA;
  u64* dst = keyB;
  for (int pass = 0; pass < 7; pass++) {
    const int shift = 32 + 4 * pass;
    u64 kreg[4]; int dreg[4], rreg[4];
    for (int s = 0; s < 4; s++) {
      const int c = wave * 4 + s;
      u64 k = src[c * 64 + lane];
      int d = (int)((k >> shift) & 15);
      u64 B0 = __ballot((d & 1) != 0);
      u64 B1 = __ballot((d & 2) != 0);
      u64 B2 = __ballot((d & 4) != 0);
      u64 B3 = __ballot((d & 8) != 0);
      u64 M = ((d & 1) ? B0 : ~B0) & ((d & 2) ? B1 : ~B1)
            & ((d & 4) ? B2 : ~B2) & ((d & 8) ? B3 : ~B3);
      rreg[s] = __popcll(M & ltmask);
      int bin = lane & 15;
      u64 Mb = ((bin & 1) ? B0 : ~B0) & ((bin & 2) ? B1 : ~B1)
             & ((bin & 4) ? B2 : ~B2) & ((bin & 8) ? B3 : ~B3);
      if (lane < 16) cnt16[bin][c] = __popcll(Mb);
      kreg[s] = k; dreg[s] = d;
    }
    __syncthreads();
    {
      int v = cnt16[wave][lane];
      int incl = v;
      for (int off2 = 1; off2 < 64; off2 <<= 1) {
        int up = __shfl_up(incl, off2, 64);
        if (lane >= off2) incl += up;
      }
      if (lane == 63) waveTot[wave] = incl;
      __syncthreads();
      if (wave == 0) {
        int tv = (lane < 16) ? waveTot[lane] : 0;
        int ts = tv;
        for (int off2 = 1; off2 < 16; off2 <<= 1) {
          int up = __shfl_up(ts, off2, 64);
          if (lane >= off2) ts += up;
        }
        if (lane < 16) waveBase[lane] = ts - tv;
      }
      __syncthreads();
      cnt16[wave][lane] = waveBase[wave] + incl - v;  // exclusive start
    }
    __syncthreads();
    for (int s = 0; s < 4; s++) {
      const int c = wave * 4 + s;
      int pos = cnt16[dreg[s]][c] + rreg[s];
      dst[pos] = kreg[s];
    }
    __syncthreads();
    u64* tmp = src; src = dst; dst = tmp;
  }
  for (int s = 0; s < 4; s++) {            // 7 passes (odd) -> result in src
    int p = tid + 1024 * s;
    keyS[f * NN + p] = src[p];
  }
}

// ---------------------------------------------------------------------------
// K2: fused per-chunk label counts + exclusive scan (1 block/frame).
// ---------------------------------------------------------------------------
__global__ __launch_bounds__(256) void countscan_kernel(
    const u64* __restrict__ keyS, const int* __restrict__ labels,
    int* __restrict__ chunkOffG, int* __restrict__ VbufL)
{
  __shared__ int cnt[64][3];
  const int f = blockIdx.x, tid = threadIdx.x;
  const int wave = tid >> 6, lane = tid & 63;
  for (int s = 0; s < 16; s++) {
    int chunk = wave * 16 + s;
    int p = chunk * 64 + lane;
    u64 kv = keyS[f * NN + p];
    bool valid = (u32)(kv >> 32) != 0xFFFFFFFFu;
    int g = (int)(kv & 0xFFFFFFFFull);
    int l = valid ? labels[f * NN + g] : 3;
    u64 B0 = __ballot((l & 1) != 0);
    u64 B1 = __ballot((l & 2) != 0);
    if (lane < 3) {
      u64 Mb = ((lane & 1) ? B0 : ~B0) & ((lane & 2) ? B1 : ~B1);
      cnt[chunk][lane] = __popcll(Mb);
    }
  }
  __syncthreads();
  if (wave == 0) {
    for (int ll = 0; ll < 3; ll++) {
      int v = cnt[lane][ll];
      int incl = v;
      for (int off2 = 1; off2 < 64; off2 <<= 1) {
        int up = __shfl_up(incl, off2, 64);
        if (lane >= off2) incl += up;
      }
      chunkOffG[(f * 64 + lane) * 3 + ll] = incl - v;
      if (lane == 63) VbufL[f * 3 + ll] = incl;
    }
  }
}

// ---------------------------------------------------------------------------
// K3 (wide): gather sorted boxes/score/label + BEV + partition scatter.
// ---------------------------------------------------------------------------
__global__ __launch_bounds__(256) void gather_kernel(
    const u64* __restrict__ keyS, const float* __restrict__ boxes,
    const float* __restrict__ scores, const int* __restrict__ labels,
    const int* __restrict__ chunkOffG,
    float* __restrict__ sboxes, float* __restrict__ sscore, float* __restrict__ slabel,
    int* __restrict__ lab_slot, int* __restrict__ loc_slot,
    int* __restrict__ pglob,
    float* __restrict__ px1, float* __restrict__ px2, float* __restrict__ py1,
    float* __restrict__ py2, float* __restrict__ parea)
{
  const int gs = blockIdx.x * 256 + threadIdx.x;
  const int f = gs >> 12, p = gs & (NN - 1);
  const int lane = threadIdx.x & 63, chunk = p >> 6;
  const u64 ltmask = (1ull << lane) - 1ull;
  u64 kv = keyS[gs];
  bool valid = (u32)(kv >> 32) != 0xFFFFFFFFu;
  int g = (int)(kv & 0xFFFFFFFFull);
  const float* bp = boxes + (size_t)(f * NN + g) * 7;
  float b0 = bp[0], b1v = bp[1], b2v = bp[2], b3 = bp[3], b4 = bp[4], b5 = bp[5], b6 = bp[6];
  int lab = labels[f * NN + g];
  const int o = f * NN + p;
  float* sb = sboxes + (size_t)o * 7;
  sb[0] = b0; sb[1] = b1v; sb[2] = b2v; sb[3] = b3; sb[4] = b4; sb[5] = b5; sb[6] = b6;
  sscore[o] = scores[f * NN + g];
  slabel[o] = (float)lab;
  int l = valid ? lab : 3;
  u64 B0 = __ballot((l & 1) != 0);
  u64 B1 = __ballot((l & 2) != 0);
  u64 M = ((l & 1) ? B0 : ~B0) & ((l & 2) ? B1 : ~B1);
  int rank = __popcll(M & ltmask);
  if (l < 3) {
    int loc = chunkOffG[(f * 64 + chunk) * 3 + l] + rank;
    int pi = (f * 3 + l) * PL + loc;
    float off = (float)l * 10000.0f;        // CLASS_OFFSET
    float cx = b0 + off, cy = b1v;
    float hx = b3 * 0.5f, hy = b4 * 0.5f;
    float x1 = cx - hx, x2 = cx + hx, y1 = cy - hy, y2 = cy + hy;
    float area = (x2 - x1) * (y2 - y1);
    pglob[pi] = p;
    px1[pi] = x1; px2[pi] = x2; py1[pi] = y1; py2[pi] = y2; parea[pi] = area;
    lab_slot[o] = l; loc_slot[o] = loc;
  } else {
    lab_slot[o] = -1; loc_slot[o] = -1;
  }
}

// ---------------------------------------------------------------------------
// Kernel B: per-partition overlap bitmask, two layouts:
//   maskP[f][slot][w]  (row-major, for cid/mm)
//   triT [fl] packed lower-triangle: stream w (= col word w, rows 64w..64W)
//             at u64 offset 64*(w*W - w*(w-1)/2); contiguous per partition
//             so the leader pass can DMA the whole triangle in one flat loop.
// ---------------------------------------------------------------------------
__global__ __launch_bounds__(256) void mask_kernel(
    const float* __restrict__ px1, const float* __restrict__ px2,
    const float* __restrict__ py1, const float* __restrict__ py2,
    const float* __restrict__ parea, const int* __restrict__ pglob,
    const int* __restrict__ VbufL,
    u64* __restrict__ maskP, u64* __restrict__ triT)
{
  __shared__ float4 cbox[1024];
  __shared__ float carea[1024];
  const int bx = blockIdx.x;                // fl*256 + rt*2 + wt
  const int fl = bx >> 8, rem = bx & 255;
  const int rt = rem >> 1, wt = rem & 1;
  const int r0 = rt * 16;
  const int Vl = VbufL[fl];
  if (r0 >= Vl) return;
  if (wt * 1024 >= Vl) return;
  const int tid = threadIdx.x;
  for (int q = tid; q < 1024; q += 256) {
    int c = fl * PL + wt * 1024 + q;
    cbox[q] = make_float4(px1[c], px2[c], py1[c], py2[c]);
    carea[q] = parea[c];
  }
  __syncthreads();
  const int row = r0 + (tid & 15);
  const int wl = tid >> 4;
  const int cw = wt * 16 + wl;
  const int nc = Vl - cw * 64;              // valid cols in this word
  if (row >= Vl || nc <= 0) return;
  const int rg = fl * PL + row;
  const float rx1 = px1[rg], rx2 = px2[rg], ry1 = py1[rg], ry2 = py2[rg], ra = parea[rg];
  u64 bits = 0;
  const int qb = wl * 64;
  for (int b = 0; b < 64; b++) {
    float4 cb = cbox[qb + b];
    float ca = carea[qb + b];
    float ix = fminf(rx2, cb.y) - fmaxf(rx1, cb.x);
    ix = fmaxf(ix, 0.0f);
    float iy = fminf(ry2, cb.w) - fmaxf(ry1, cb.z);
    iy = fmaxf(iy, 0.0f);
    float inter = ix * iy;
    float den = fmaxf((ra + ca) - inter, 1e-6f);
    float iou = inter / den;
    bits |= ((u64)(iou > 0.3f)) << b;       // IOU_THRES
  }
  if (nc < 64) bits &= (1ull << nc) - 1ull;
  const int f = fl / 3;
  const int p = pglob[fl * PL + row];
  maskP[((size_t)f * NN + p) * WL + cw] = bits;
  if (row >= 64 * cw) {                     // lower triangle only
    const int W = (Vl + 63) >> 6;
    int base = 64 * (cw * W - (cw * (cw - 1)) / 2);
    triT[(size_t)fl * TRI_CAP + base + (row - 64 * cw)] = bits;
  }
}

// ---------------------------------------------------------------------------
// Kernel C: leader pass. ONE WAVE per (frame,label).
// DMA the ENTIRE packed lower-triangle (512*W(W+1)/2 B, <=153.6KB at WF=24)
// into LDS once (flat contiguous chunk loop, batch-drained every 48 chunks),
// then a serial loop with ZERO memory ops except LDS. Rows in [Vl,64W) are
// unwritten garbage but provably never consumed (greedy rem is alive-masked;
// apply only clears already-zero alive bits). Fallback (W>WF, +15.7 sigma):
// plain global reads of the packed layout.
// ---------------------------------------------------------------------------
__global__ __launch_bounds__(64) void nms_kernel(
    const u64* __restrict__ triT, const int* __restrict__ VbufL,
    u64* __restrict__ leadersP)
{
  __shared__ u64 tri[64 * (WF * (WF + 1) / 2) + 128];  // 153.6KB + 1KB slack
  const int fl = blockIdx.x, lane = threadIdx.x;
  const int Vl = VbufL[fl];
  const int W = (Vl + 63) >> 6;
  const u64* mT = triT + (size_t)fl * TRI_CAP;
  u64 alive = 0;
  if (lane < WL) {
    int rb = Vl - 64 * lane;
    alive = (rb >= 64) ? ~0ull : ((rb > 0) ? ((1ull << rb) - 1ull) : 0ull);
  }
  u64 myLead = 0;

  if (W > 0 && W <= WF) {
    // ---- prime: whole packed triangle -> LDS (flat contiguous) ----
    const int totw = 64 * (W * (W + 1) / 2);          // u64 count
    const int nch = (totw * 8 + 1023) >> 10;          // 1KB chunks
    const char* g = (const char*)mT;
    char* l = (char*)tri;
    int batch = 0;
    for (int it = 0; it < nch; it++) {
      __builtin_amdgcn_global_load_lds(
          (const __attribute__((address_space(1))) unsigned int*)(g + (size_t)it * 1024 + (size_t)lane * 16),
          (__attribute__((address_space(3))) unsigned int*)(l + (size_t)it * 1024),
          16, 0, 0);
      if (++batch == 48) {                  // stay within vmcnt range
        asm volatile("s_waitcnt vmcnt(0)" ::: "memory");
        batch = 0;
      }
    }
    asm volatile("s_waitcnt vmcnt(0)" ::: "memory");
    // ---- serial loop: pure LDS/VALU ----
    int offw = 0;
    for (int w = 0; w < W; w++) {
      const u64* strm = tri + offw;         // stream w: rows 64w..64W
      u64 D = strm[lane];                   // diag: row 64w+lane, word w
      u64 lead = greedy64(D, readlane64(alive, w));
      if (lane == w) myLead = lead;
      if (lead) {
        int v = w + 1;
        for (; v + 3 < W; v += 4) {         // 4 independent ds_reads/batch
          u64 a0 = strm[64 * (v - w) + lane];
          u64 a1 = strm[64 * (v + 1 - w) + lane];
          u64 a2 = strm[64 * (v + 2 - w) + lane];
          u64 a3 = strm[64 * (v + 3 - w) + lane];
          u64 c0 = __ballot((a0 & lead) != 0ull);
          u64 c1 = __ballot((a1 & lead) != 0ull);
          u64 c2 = __ballot((a2 & lead) != 0ull);
          u64 c3 = __ballot((a3 & lead) != 0ull);
          if (lane == v)     alive &= ~c0;
          if (lane == v + 1) alive &= ~c1;
          if (lane == v + 2) alive &= ~c2;
          if (lane == v + 3) alive &= ~c3;
        }
        for (; v < W; v++) {
          u64 a0 = strm[64 * (v - w) + lane];
          u64 c0 = __ballot((a0 & lead) != 0ull);
          if (lane == v) alive &= ~c0;
        }
      }
      offw += 64 * (W - w);
    }
  } else if (W > 0) {
    // ---- fallback (W > WF): plain global reads of packed layout ----
    int offw = 0;
    for (int w = 0; w < W; w++) {
      const u64* strm = mT + offw;
      u64 D = strm[lane];
      u64 lead = greedy64(D, readlane64(alive, w));
      if (lane == w) myLead = lead;
      if (lead) {
        for (int v = w + 1; v < W; v++) {
          u64 a0 = strm[64 * (v - w) + lane];
          u64 c0 = __ballot((a0 & lead) != 0ull);
          if (lane == v) alive &= ~c0;
        }
      }
      offw += 64 * (W - w);
    }
  }
  if (lane < WL) leadersP[fl * WL + lane] = myLead;
}

// ---------------------------------------------------------------------------
// Kernel D: parallel cid (partition-local). One wave per slot.
// ---------------------------------------------------------------------------
__global__ __launch_bounds__(256) void cid_kernel(
    const u64* __restrict__ maskP, const u64* __restrict__ leadersP,
    const int* __restrict__ lab_slot, const int* __restrict__ loc_slot,
    const int* __restrict__ VbufL, int* __restrict__ cidP)
{
  const int g = blockIdx.x * 4 + (threadIdx.x >> 6);
  const int lane = threadIdx.x & 63;
  const int f = g >> 12, p = g & (NN - 1);
  const int l = lab_slot[f * NN + p];
  if (l < 0) return;
  const int fl = f * 3 + l;
  const int loc = loc_slot[f * NN + p];
  const int Wl = (VbufL[fl] + 63) >> 6;
  u64 L = 0, m = 0;
  if (lane < Wl) {
    L = leadersP[fl * WL + lane];
    m = maskP[((size_t)f * NN + p) * WL + lane];
  }
  const int g6 = loc >> 6, b6 = loc & 63;
  u64 pmask = (lane < g6) ? ~0ull
            : (lane == g6 ? ((b6 == 63) ? ~0ull : ((1ull << (b6 + 1)) - 1ull)) : 0ull);
  u64 v = m & L & pmask;
  u64 bl = __ballot(v != 0ull);
  int cid = -1;
  if (bl != 0ull) {
    int w = __builtin_ctzll(bl);
    u64 vw = shfl64(v, w);
    cid = w * 64 + __builtin_ctzll(vw);
  }
  if (lane == 0) cidP[fl * PL + loc] = cid;
}

// ---------------------------------------------------------------------------
// Kernel E: fused members + merge. One 64-thread block per row.
// ---------------------------------------------------------------------------
__global__ __launch_bounds__(64) void mm_kernel(
    const u64* __restrict__ maskP, const u64* __restrict__ leadersP,
    const int* __restrict__ cidP, const int* __restrict__ lab_slot,
    const int* __restrict__ loc_slot, const int* __restrict__ pglob,
    const int* __restrict__ VbufL,
    const float* __restrict__ sboxes, const float* __restrict__ sscore,
    const float* __restrict__ slabel,
    const float* __restrict__ W1, const float* __restrict__ b1,
    const float* __restrict__ W2, const float* __restrict__ b2,
    float* __restrict__ out)
{
  const int bi = blockIdx.x;
  const int f = bi >> 12, i = bi & (NN - 1);
  const int lane = threadIdx.x;
  const int o = f * NN + i;
  float* info = out + (size_t)o * 9;
  float* lead = out + (size_t)BF * NN * 9 + o;
  const int l = lab_slot[o];
  bool isLead = false;
  int loc = 0, fl = 0;
  if (l >= 0) {
    fl = f * 3 + l;
    loc = loc_slot[o];
    isLead = (leadersP[fl * WL + (loc >> 6)] >> (loc & 63)) & 1ull;
  }
  if (!isLead) {
    if (lane < 9) info[lane] = 0.0f;
    if (lane == 0) *lead = 0.0f;
    return;
  }
  __shared__ int mlist[MAXC];
  __shared__ float mb[MAXC][7];
  __shared__ float lg[MAXC];
  __shared__ float wn[MAXC];
  const u64* mrow = maskP + (size_t)o * WL;
  const int Wl = (VbufL[fl] + 63) >> 6;
  int total = 0;
  for (int w = loc >> 6; w < Wl && total < MAXC; w++) {
    u64 word = mrow[w];
    int pos = w * 64 + lane;
    bool cand = ((word >> lane) & 1ull) && (cidP[fl * PL + pos] == loc);
    u64 mbal = __ballot(cand);
    int r = __popcll(mbal & ((1ull << lane) - 1ull));
    int slot = total + r;
    if (cand && slot < MAXC) mlist[slot] = pglob[fl * PL + pos];
    total += __popcll(mbal);
  }
  const int cnt = min(total, MAXC);
  __syncthreads();
  if (lane < cnt) {
    int j = mlist[lane];
    const float* bp = sboxes + (size_t)(f * NN + j) * 7;
    for (int d = 0; d < 7; d++) mb[lane][d] = bp[d];
  }
  float w1r[7];
  for (int d = 0; d < 7; d++) w1r[d] = W1[d * 64 + lane];
  const float b1c = b1[lane], w2c = W2[lane], b2v = b2[0];
  __syncthreads();
  for (int s = 0; s < cnt; s++) {
    float t = b1c;
    for (int d = 0; d < 7; d++) t += mb[s][d] * w1r[d];
    float h = fmaxf(t, 0.0f);
    float v = h * w2c;
    for (int off2 = 32; off2 > 0; off2 >>= 1) v += __shfl_xor(v, off2, 64);
    if (lane == 0) lg[s] = v + b2v;
  }
  __syncthreads();
  float mx = -1e30f;
  for (int s = 0; s < cnt; s++) mx = fmaxf(mx, lg[s]);
  float den = 0.0f;
  for (int s = 0; s < cnt; s++) den += expf(lg[s] - mx);
  if (lane < cnt) wn[lane] = expf(lg[lane] - mx) / den;
  __syncthreads();
  float val = 0.0f;
  if (lane < 7) {
    float acc = 0.0f;
    for (int s = 0; s < cnt; s++) acc += wn[s] * mb[s][lane];
    val = acc;
    if (lane >= 3 && lane <= 5 && val <= 0.0f) val = sboxes[(size_t)o * 7 + lane];
  } else if (lane == 7) {
    val = sscore[o];
  } else if (lane == 8) {
    val = slabel[o];
  }
  if (lane < 9) info[lane] = val;
  if (lane == 0) *lead = 1.0f;
}

// ---------------------------------------------------------------------------
extern "C" void kernel_launch(void* const* d_in, const int* in_sizes, int n_in,
                              void* d_out, int out_size, void* d_ws, size_t ws_size,
                              hipStream_t stream)
{
  const float* boxes  = (const float*)d_in[0];
  const float* scores = (const float*)d_in[1];
  const int*   labels = (const int*)d_in[2];
  const float* W1     = (const float*)d_in[3];
  const float* b1     = (const float*)d_in[4];
  const float* W2     = (const float*)d_in[5];
  const float* b2     = (const float*)d_in[6];
  float* out = (float*)d_out;

  char* ws = (char*)d_ws;
  size_t off = 0;
  auto alloc = [&](size_t bytes) -> void* {
    void* p = ws + off;
    off = (off + bytes + 255) & ~(size_t)255;
    return p;
  };
  u64*   keyS    = (u64*)  alloc((size_t)BF * NN * 8);
  int*   chunkOffG=(int*)  alloc((size_t)BF * 64 * 3 * 4);
  float* sboxes  = (float*)alloc((size_t)BF * NN * 7 * 4);
  float* sscore  = (float*)alloc((size_t)BF * NN * 4);
  float* slabel  = (float*)alloc((size_t)BF * NN * 4);
  int*   lab_slot= (int*)  alloc((size_t)BF * NN * 4);
  int*   loc_slot= (int*)  alloc((size_t)BF * NN * 4);
  int*   pglob   = (int*)  alloc((size_t)BF * 3 * PL * 4);
  float* px1     = (float*)alloc((size_t)BF * 3 * PL * 4);
  float* px2     = (float*)alloc((size_t)BF * 3 * PL * 4);
  float* py1     = (float*)alloc((size_t)BF * 3 * PL * 4);
  float* py2     = (float*)alloc((size_t)BF * 3 * PL * 4);
  float* parea   = (float*)alloc((size_t)BF * 3 * PL * 4);
  int*   VbufL   = (int*)  alloc((size_t)BF * 3 * 4);
  u64*   leadersP= (u64*)  alloc((size_t)BF * 3 * WL * 8);
  int*   cidP    = (int*)  alloc((size_t)BF * 3 * PL * 4);
  u64*   maskP   = (u64*)  alloc((size_t)BF * NN * WL * 8);        // 4 MB
  u64*   triT    = (u64*)  alloc((size_t)BF * 3 * TRI_CAP * 8);    // 3.2 MB
  (void)  alloc(32768);                     // DMA overrun slack after triT

  sort_kernel<<<BF, 1024, 0, stream>>>(scores, keyS);
  countscan_kernel<<<BF, 256, 0, stream>>>(keyS, labels, chunkOffG, VbufL);
  gather_kernel<<<BF * NN / 256, 256, 0, stream>>>(keyS, boxes, scores, labels,
                                                   chunkOffG, sboxes, sscore,
                                                   slabel, lab_slot, loc_slot,
                                                   pglob, px1, px2, py1, py2,
                                                   parea);
  mask_kernel<<<BF * 3 * 256, 256, 0, stream>>>(px1, px2, py1, py2, parea,
                                                pglob, VbufL, maskP, triT);
  nms_kernel<<<BF * 3, 64, 0, stream>>>(triT, VbufL, leadersP);
  cid_kernel<<<BF * NN / 4, 256, 0, stream>>>(maskP, leadersP, lab_slot,
                                              loc_slot, VbufL, cidP);
  mm_kernel<<<BF * NN, 64, 0, stream>>>(maskP, leadersP, cidP, lab_slot,
                                        loc_slot, pglob, VbufL, sboxes,
                                        sscore, slabel, W1, b1, W2, b2, out);
}

// Round 11
// 165.565 us; speedup vs baseline: 1.2101x; 1.2031x over previous
//
#include <hip/hip_runtime.h>
#include <stdint.h>

// Match numpy reference bit-exactly on the IoU path: no fma contraction.
#pragma clang fp contract(off)

#define BF 4
#define NN 4096
#define MAXC 16
#define PL 2048   // per-label partition capacity
#define WL 32     // PL/64 words per partition row
#define WF 24     // full-LDS leader-pass capacity (Vl<=1536; +15.7 sigma)
#define TRI_CAP (64 * (WL * (WL + 1) / 2))  // per-fl packed triangle capacity (u64)

typedef unsigned long long u64;
typedef uint32_t u32;

__device__ __forceinline__ u64 shfl64(u64 v, int src) {
  return (u64)__shfl((long long)v, src, 64);
}
__device__ __forceinline__ u64 readlane64(u64 v, int l) {
  u32 lo = (u32)__builtin_amdgcn_readlane((int)(u32)v, l);
  u32 hi = (u32)__builtin_amdgcn_readlane((int)(u32)(v >> 32), l);
  return ((u64)hi << 32) | lo;
}
// Greedy NMS inside one 64-row block with ISO bulk-accept:
// a row with D & rem == onlyme (no other alive in-block overlap) is provably
// a leader and claims only itself -> accept ALL such rows with one ballot.
// Order-equivalence: if greedy's lowest bit is iso it claims itself only;
// non-iso claim sets are unchanged by removing isos; isos remain iso as rem
// shrinks. Serial steps remain only for multi-member clusters (~4x fewer).
__device__ __forceinline__ u64 greedy64_iso(u64 D, u64 rem, u64 onlyme) {
  u64 lead = 0;
  while (rem) {
    u64 t = D & rem;
    u64 iso = __ballot(t == onlyme) & rem;  // bulk singleton leaders
    lead |= iso;
    rem &= ~iso;
    if (!rem) break;
    int b = __builtin_ctzll(rem);           // serial step 1 (multi-cluster)
    lead |= 1ull << b;
    rem &= ~readlane64(D, b);
    if (!rem) break;
    b = __builtin_ctzll(rem);               // serial step 2 (no re-iso needed)
    lead |= 1ull << b;
    rem &= ~readlane64(D, b);
  }
  return lead;
}

// ---------------------------------------------------------------------------
// K1: per-frame stable descending sort by score — LDS radix (1 block/frame).
// 7 passes x 4 bits over hi32 bits [32..59]; top-nibble pass provably
// redundant for these inputs. Bit-sliced ballot ranking.
// ---------------------------------------------------------------------------
__global__ __launch_bounds__(1024) void sort_kernel(
    const float* __restrict__ scores, u64* __restrict__ keyS)
{
  __shared__ u64 keyA[NN];                  // 32 KB
  __shared__ u64 keyB[NN];                  // 32 KB
  __shared__ int cnt16[16][65];             // [bin][chunk], padded
  __shared__ int waveTot[16];
  __shared__ int waveBase[16];
  const int f = blockIdx.x, tid = threadIdx.x;
  const int wave = tid >> 6, lane = tid & 63;
  const u64 ltmask = (1ull << lane) - 1ull;

  for (int s = 0; s < 4; s++) {
    int idx = tid + 1024 * s;
    float sc = scores[f * NN + idx];
    bool valid = sc > 0.2f;                 // COND_THRES
    u32 bits = __float_as_uint(sc);
    u32 m = bits ^ ((bits >> 31) ? 0xFFFFFFFFu : 0x80000000u);
    u32 hi = valid ? ~m : 0xFFFFFFFFu;      // smaller = higher score
    keyA[idx] = ((u64)hi << 32) | (u32)idx; // idx payload = stable tie-break
  }
  __syncthreads();

  u64* src = keyA;
  u64* dst = keyB;
  for (int pass = 0; pass < 7; pass++) {
    const int shift = 32 + 4 * pass;
    u64 kreg[4]; int dreg[4], rreg[4];
    for (int s = 0; s < 4; s++) {
      const int c = wave * 4 + s;
      u64 k = src[c * 64 + lane];
      int d = (int)((k >> shift) & 15);
      u64 B0 = __ballot((d & 1) != 0);
      u64 B1 = __ballot((d & 2) != 0);
      u64 B2 = __ballot((d & 4) != 0);
      u64 B3 = __ballot((d & 8) != 0);
      u64 M = ((d & 1) ? B0 : ~B0) & ((d & 2) ? B1 : ~B1)
            & ((d & 4) ? B2 : ~B2) & ((d & 8) ? B3 : ~B3);
      rreg[s] = __popcll(M & ltmask);
      int bin = lane & 15;
      u64 Mb = ((bin & 1) ? B0 : ~B0) & ((bin & 2) ? B1 : ~B1)
             & ((bin & 4) ? B2 : ~B2) & ((bin & 8) ? B3 : ~B3);
      if (lane < 16) cnt16[bin][c] = __popcll(Mb);
      kreg[s] = k; dreg[s] = d;
    }
    __syncthreads();
    {
      int v = cnt16[wave][lane];
      int incl = v;
      for (int off2 = 1; off2 < 64; off2 <<= 1) {
        int up = __shfl_up(incl, off2, 64);
        if (lane >= off2) incl += up;
      }
      if (lane == 63) waveTot[wave] = incl;
      __syncthreads();
      if (wave == 0) {
        int tv = (lane < 16) ? waveTot[lane] : 0;
        int ts = tv;
        for (int off2 = 1; off2 < 16; off2 <<= 1) {
          int up = __shfl_up(ts, off2, 64);
          if (lane >= off2) ts += up;
        }
        if (lane < 16) waveBase[lane] = ts - tv;
      }
      __syncthreads();
      cnt16[wave][lane] = waveBase[wave] + incl - v;  // exclusive start
    }
    __syncthreads();
    for (int s = 0; s < 4; s++) {
      const int c = wave * 4 + s;
      int pos = cnt16[dreg[s]][c] + rreg[s];
      dst[pos] = kreg[s];
    }
    __syncthreads();
    u64* tmp = src; src = dst; dst = tmp;
  }
  for (int s = 0; s < 4; s++) {            // 7 passes (odd) -> result in src
    int p = tid + 1024 * s;
    keyS[f * NN + p] = src[p];
  }
}

// ---------------------------------------------------------------------------
// K2: fused per-chunk label counts + exclusive scan (1 block/frame).
// ---------------------------------------------------------------------------
__global__ __launch_bounds__(256) void countscan_kernel(
    const u64* __restrict__ keyS, const int* __restrict__ labels,
    int* __restrict__ chunkOffG, int* __restrict__ VbufL)
{
  __shared__ int cnt[64][3];
  const int f = blockIdx.x, tid = threadIdx.x;
  const int wave = tid >> 6, lane = tid & 63;
  for (int s = 0; s < 16; s++) {
    int chunk = wave * 16 + s;
    int p = chunk * 64 + lane;
    u64 kv = keyS[f * NN + p];
    bool valid = (u32)(kv >> 32) != 0xFFFFFFFFu;
    int g = (int)(kv & 0xFFFFFFFFull);
    int l = valid ? labels[f * NN + g] : 3;
    u64 B0 = __ballot((l & 1) != 0);
    u64 B1 = __ballot((l & 2) != 0);
    if (lane < 3) {
      u64 Mb = ((lane & 1) ? B0 : ~B0) & ((lane & 2) ? B1 : ~B1);
      cnt[chunk][lane] = __popcll(Mb);
    }
  }
  __syncthreads();
  if (wave == 0) {
    for (int ll = 0; ll < 3; ll++) {
      int v = cnt[lane][ll];
      int incl = v;
      for (int off2 = 1; off2 < 64; off2 <<= 1) {
        int up = __shfl_up(incl, off2, 64);
        if (lane >= off2) incl += up;
      }
      chunkOffG[(f * 64 + lane) * 3 + ll] = incl - v;
      if (lane == 63) VbufL[f * 3 + ll] = incl;
    }
  }
}

// ---------------------------------------------------------------------------
// K3 (wide): gather sorted boxes/score/label + BEV + partition scatter.
// ---------------------------------------------------------------------------
__global__ __launch_bounds__(256) void gather_kernel(
    const u64* __restrict__ keyS, const float* __restrict__ boxes,
    const float* __restrict__ scores, const int* __restrict__ labels,
    const int* __restrict__ chunkOffG,
    float* __restrict__ sboxes, float* __restrict__ sscore, float* __restrict__ slabel,
    int* __restrict__ lab_slot, int* __restrict__ loc_slot,
    int* __restrict__ pglob,
    float* __restrict__ px1, float* __restrict__ px2, float* __restrict__ py1,
    float* __restrict__ py2, float* __restrict__ parea)
{
  const int gs = blockIdx.x * 256 + threadIdx.x;
  const int f = gs >> 12, p = gs & (NN - 1);
  const int lane = threadIdx.x & 63, chunk = p >> 6;
  const u64 ltmask = (1ull << lane) - 1ull;
  u64 kv = keyS[gs];
  bool valid = (u32)(kv >> 32) != 0xFFFFFFFFu;
  int g = (int)(kv & 0xFFFFFFFFull);
  const float* bp = boxes + (size_t)(f * NN + g) * 7;
  float b0 = bp[0], b1v = bp[1], b2v = bp[2], b3 = bp[3], b4 = bp[4], b5 = bp[5], b6 = bp[6];
  int lab = labels[f * NN + g];
  const int o = f * NN + p;
  float* sb = sboxes + (size_t)o * 7;
  sb[0] = b0; sb[1] = b1v; sb[2] = b2v; sb[3] = b3; sb[4] = b4; sb[5] = b5; sb[6] = b6;
  sscore[o] = scores[f * NN + g];
  slabel[o] = (float)lab;
  int l = valid ? lab : 3;
  u64 B0 = __ballot((l & 1) != 0);
  u64 B1 = __ballot((l & 2) != 0);
  u64 M = ((l & 1) ? B0 : ~B0) & ((l & 2) ? B1 : ~B1);
  int rank = __popcll(M & ltmask);
  if (l < 3) {
    int loc = chunkOffG[(f * 64 + chunk) * 3 + l] + rank;
    int pi = (f * 3 + l) * PL + loc;
    float off = (float)l * 10000.0f;        // CLASS_OFFSET
    float cx = b0 + off, cy = b1v;
    float hx = b3 * 0.5f, hy = b4 * 0.5f;
    float x1 = cx - hx, x2 = cx + hx, y1 = cy - hy, y2 = cy + hy;
    float area = (x2 - x1) * (y2 - y1);
    pglob[pi] = p;
    px1[pi] = x1; px2[pi] = x2; py1[pi] = y1; py2[pi] = y2; parea[pi] = area;
    lab_slot[o] = l; loc_slot[o] = loc;
  } else {
    lab_slot[o] = -1; loc_slot[o] = -1;
  }
}

// ---------------------------------------------------------------------------
// Kernel B: per-partition overlap bitmask, two layouts:
//   maskP[f][slot][w]  (row-major, for cid/mm)
//   triT [fl] packed lower-triangle: stream w at u64 offset
//             64*(w*W - w*(w-1)/2); contiguous per partition.
// ---------------------------------------------------------------------------
__global__ __launch_bounds__(256) void mask_kernel(
    const float* __restrict__ px1, const float* __restrict__ px2,
    const float* __restrict__ py1, const float* __restrict__ py2,
    const float* __restrict__ parea, const int* __restrict__ pglob,
    const int* __restrict__ VbufL,
    u64* __restrict__ maskP, u64* __restrict__ triT)
{
  __shared__ float4 cbox[1024];
  __shared__ float carea[1024];
  const int bx = blockIdx.x;                // fl*256 + rt*2 + wt
  const int fl = bx >> 8, rem = bx & 255;
  const int rt = rem >> 1, wt = rem & 1;
  const int r0 = rt * 16;
  const int Vl = VbufL[fl];
  if (r0 >= Vl) return;
  if (wt * 1024 >= Vl) return;
  const int tid = threadIdx.x;
  for (int q = tid; q < 1024; q += 256) {
    int c = fl * PL + wt * 1024 + q;
    cbox[q] = make_float4(px1[c], px2[c], py1[c], py2[c]);
    carea[q] = parea[c];
  }
  __syncthreads();
  const int row = r0 + (tid & 15);
  const int wl = tid >> 4;
  const int cw = wt * 16 + wl;
  const int nc = Vl - cw * 64;              // valid cols in this word
  if (row >= Vl || nc <= 0) return;
  const int rg = fl * PL + row;
  const float rx1 = px1[rg], rx2 = px2[rg], ry1 = py1[rg], ry2 = py2[rg], ra = parea[rg];
  u64 bits = 0;
  const int qb = wl * 64;
  for (int b = 0; b < 64; b++) {
    float4 cb = cbox[qb + b];
    float ca = carea[qb + b];
    float ix = fminf(rx2, cb.y) - fmaxf(rx1, cb.x);
    ix = fmaxf(ix, 0.0f);
    float iy = fminf(ry2, cb.w) - fmaxf(ry1, cb.z);
    iy = fmaxf(iy, 0.0f);
    float inter = ix * iy;
    float den = fmaxf((ra + ca) - inter, 1e-6f);
    float iou = inter / den;
    bits |= ((u64)(iou > 0.3f)) << b;       // IOU_THRES
  }
  if (nc < 64) bits &= (1ull << nc) - 1ull;
  const int f = fl / 3;
  const int p = pglob[fl * PL + row];
  maskP[((size_t)f * NN + p) * WL + cw] = bits;
  if (row >= 64 * cw) {                     // lower triangle only
    const int W = (Vl + 63) >> 6;
    int base = 64 * (cw * W - (cw * (cw - 1)) / 2);
    triT[(size_t)fl * TRI_CAP + base + (row - 64 * cw)] = bits;
  }
}

// ---------------------------------------------------------------------------
// Kernel C: leader pass. ONE WAVE per (frame,label).
// Whole packed lower-triangle DMA'd to LDS once; serial loop is pure LDS/VALU
// with (R11) iso bulk-accept greedy + next-diag LDS prefetch. Rows in
// [Vl,64W) are unwritten garbage but provably never consumed.
// ---------------------------------------------------------------------------
__global__ __launch_bounds__(64) void nms_kernel(
    const u64* __restrict__ triT, const int* __restrict__ VbufL,
    u64* __restrict__ leadersP)
{
  __shared__ u64 tri[64 * (WF * (WF + 1) / 2) + 128];  // 153.6KB + 1KB slack
  const int fl = blockIdx.x, lane = threadIdx.x;
  const int Vl = VbufL[fl];
  const int W = (Vl + 63) >> 6;
  const u64* mT = triT + (size_t)fl * TRI_CAP;
  const u64 onlyme = 1ull << lane;
  u64 alive = 0;
  if (lane < WL) {
    int rb = Vl - 64 * lane;
    alive = (rb >= 64) ? ~0ull : ((rb > 0) ? ((1ull << rb) - 1ull) : 0ull);
  }
  u64 myLead = 0;

  if (W > 0 && W <= WF) {
    // ---- prime: whole packed triangle -> LDS (flat contiguous) ----
    const int totw = 64 * (W * (W + 1) / 2);          // u64 count
    const int nch = (totw * 8 + 1023) >> 10;          // 1KB chunks
    const char* g = (const char*)mT;
    char* l = (char*)tri;
    int batch = 0;
    for (int it = 0; it < nch; it++) {
      __builtin_amdgcn_global_load_lds(
          (const __attribute__((address_space(1))) unsigned int*)(g + (size_t)it * 1024 + (size_t)lane * 16),
          (__attribute__((address_space(3))) unsigned int*)(l + (size_t)it * 1024),
          16, 0, 0);
      if (++batch == 48) {                  // stay within vmcnt range
        asm volatile("s_waitcnt vmcnt(0)" ::: "memory");
        batch = 0;
      }
    }
    asm volatile("s_waitcnt vmcnt(0)" ::: "memory");
    // ---- serial loop: pure LDS/VALU ----
    int offw = 0;
    u64 D = tri[lane];                      // diag of block 0
    for (int w = 0; w < W; w++) {
      const int offw_next = offw + 64 * (W - w);
      u64 Dnext = (w + 1 < W) ? tri[offw_next + lane] : 0;  // prefetch
      u64 lead = greedy64_iso(D, readlane64(alive, w), onlyme);
      if (lane == w) myLead = lead;
      if (lead) {
        const u64* strm = tri + offw;
        int v = w + 1;
        for (; v + 3 < W; v += 4) {         // 4 independent ds_reads/batch
          u64 a0 = strm[64 * (v - w) + lane];
          u64 a1 = strm[64 * (v + 1 - w) + lane];
          u64 a2 = strm[64 * (v + 2 - w) + lane];
          u64 a3 = strm[64 * (v + 3 - w) + lane];
          u64 c0 = __ballot((a0 & lead) != 0ull);
          u64 c1 = __ballot((a1 & lead) != 0ull);
          u64 c2 = __ballot((a2 & lead) != 0ull);
          u64 c3 = __ballot((a3 & lead) != 0ull);
          if (lane == v)     alive &= ~c0;
          if (lane == v + 1) alive &= ~c1;
          if (lane == v + 2) alive &= ~c2;
          if (lane == v + 3) alive &= ~c3;
        }
        for (; v < W; v++) {
          u64 a0 = strm[64 * (v - w) + lane];
          u64 c0 = __ballot((a0 & lead) != 0ull);
          if (lane == v) alive &= ~c0;
        }
      }
      D = Dnext;
      offw = offw_next;
    }
  } else if (W > 0) {
    // ---- fallback (W > WF): plain global reads of packed layout ----
    int offw = 0;
    for (int w = 0; w < W; w++) {
      const u64* strm = mT + offw;
      u64 D = strm[lane];
      u64 lead = greedy64_iso(D, readlane64(alive, w), onlyme);
      if (lane == w) myLead = lead;
      if (lead) {
        for (int v = w + 1; v < W; v++) {
          u64 a0 = strm[64 * (v - w) + lane];
          u64 c0 = __ballot((a0 & lead) != 0ull);
          if (lane == v) alive &= ~c0;
        }
      }
      offw += 64 * (W - w);
    }
  }
  if (lane < WL) leadersP[fl * WL + lane] = myLead;
}

// ---------------------------------------------------------------------------
// Kernel D: parallel cid (partition-local). One wave per slot.
// ---------------------------------------------------------------------------
__global__ __launch_bounds__(256) void cid_kernel(
    const u64* __restrict__ maskP, const u64* __restrict__ leadersP,
    const int* __restrict__ lab_slot, const int* __restrict__ loc_slot,
    const int* __restrict__ VbufL, int* __restrict__ cidP)
{
  const int g = blockIdx.x * 4 + (threadIdx.x >> 6);
  const int lane = threadIdx.x & 63;
  const int f = g >> 12, p = g & (NN - 1);
  const int l = lab_slot[f * NN + p];
  if (l < 0) return;
  const int fl = f * 3 + l;
  const int loc = loc_slot[f * NN + p];
  const int Wl = (VbufL[fl] + 63) >> 6;
  u64 L = 0, m = 0;
  if (lane < Wl) {
    L = leadersP[fl * WL + lane];
    m = maskP[((size_t)f * NN + p) * WL + lane];
  }
  const int g6 = loc >> 6, b6 = loc & 63;
  u64 pmask = (lane < g6) ? ~0ull
            : (lane == g6 ? ((b6 == 63) ? ~0ull : ((1ull << (b6 + 1)) - 1ull)) : 0ull);
  u64 v = m & L & pmask;
  u64 bl = __ballot(v != 0ull);
  int cid = -1;
  if (bl != 0ull) {
    int w = __builtin_ctzll(bl);
    u64 vw = shfl64(v, w);
    cid = w * 64 + __builtin_ctzll(vw);
  }
  if (lane == 0) cidP[fl * PL + loc] = cid;
}

// ---------------------------------------------------------------------------
// Kernel E: fused members + merge. One 64-thread block per row.
// ---------------------------------------------------------------------------
__global__ __launch_bounds__(64) void mm_kernel(
    const u64* __restrict__ maskP, const u64* __restrict__ leadersP,
    const int* __restrict__ cidP, const int* __restrict__ lab_slot,
    const int* __restrict__ loc_slot, const int* __restrict__ pglob,
    const int* __restrict__ VbufL,
    const float* __restrict__ sboxes, const float* __restrict__ sscore,
    const float* __restrict__ slabel,
    const float* __restrict__ W1, const float* __restrict__ b1,
    const float* __restrict__ W2, const float* __restrict__ b2,
    float* __restrict__ out)
{
  const int bi = blockIdx.x;
  const int f = bi >> 12, i = bi & (NN - 1);
  const int lane = threadIdx.x;
  const int o = f * NN + i;
  float* info = out + (size_t)o * 9;
  float* lead = out + (size_t)BF * NN * 9 + o;
  const int l = lab_slot[o];
  bool isLead = false;
  int loc = 0, fl = 0;
  if (l >= 0) {
    fl = f * 3 + l;
    loc = loc_slot[o];
    isLead = (leadersP[fl * WL + (loc >> 6)] >> (loc & 63)) & 1ull;
  }
  if (!isLead) {
    if (lane < 9) info[lane] = 0.0f;
    if (lane == 0) *lead = 0.0f;
    return;
  }
  __shared__ int mlist[MAXC];
  __shared__ float mb[MAXC][7];
  __shared__ float lg[MAXC];
  __shared__ float wn[MAXC];
  const u64* mrow = maskP + (size_t)o * WL;
  const int Wl = (VbufL[fl] + 63) >> 6;
  int total = 0;
  for (int w = loc >> 6; w < Wl && total < MAXC; w++) {
    u64 word = mrow[w];
    int pos = w * 64 + lane;
    bool cand = ((word >> lane) & 1ull) && (cidP[fl * PL + pos] == loc);
    u64 mbal = __ballot(cand);
    int r = __popcll(mbal & ((1ull << lane) - 1ull));
    int slot = total + r;
    if (cand && slot < MAXC) mlist[slot] = pglob[fl * PL + pos];
    total += __popcll(mbal);
  }
  const int cnt = min(total, MAXC);
  __syncthreads();
  if (lane < cnt) {
    int j = mlist[lane];
    const float* bp = sboxes + (size_t)(f * NN + j) * 7;
    for (int d = 0; d < 7; d++) mb[lane][d] = bp[d];
  }
  float w1r[7];
  for (int d = 0; d < 7; d++) w1r[d] = W1[d * 64 + lane];
  const float b1c = b1[lane], w2c = W2[lane], b2v = b2[0];
  __syncthreads();
  for (int s = 0; s < cnt; s++) {
    float t = b1c;
    for (int d = 0; d < 7; d++) t += mb[s][d] * w1r[d];
    float h = fmaxf(t, 0.0f);
    float v = h * w2c;
    for (int off2 = 32; off2 > 0; off2 >>= 1) v += __shfl_xor(v, off2, 64);
    if (lane == 0) lg[s] = v + b2v;
  }
  __syncthreads();
  float mx = -1e30f;
  for (int s = 0; s < cnt; s++) mx = fmaxf(mx, lg[s]);
  float den = 0.0f;
  for (int s = 0; s < cnt; s++) den += expf(lg[s] - mx);
  if (lane < cnt) wn[lane] = expf(lg[lane] - mx) / den;
  __syncthreads();
  float val = 0.0f;
  if (lane < 7) {
    float acc = 0.0f;
    for (int s = 0; s < cnt; s++) acc += wn[s] * mb[s][lane];
    val = acc;
    if (lane >= 3 && lane <= 5 && val <= 0.0f) val = sboxes[(size_t)o * 7 + lane];
  } else if (lane == 7) {
    val = sscore[o];
  } else if (lane == 8) {
    val = slabel[o];
  }
  if (lane < 9) info[lane] = val;
  if (lane == 0) *lead = 1.0f;
}

// ---------------------------------------------------------------------------
extern "C" void kernel_launch(void* const* d_in, const int* in_sizes, int n_in,
                              void* d_out, int out_size, void* d_ws, size_t ws_size,
                              hipStream_t stream)
{
  const float* boxes  = (const float*)d_in[0];
  const float* scores = (const float*)d_in[1];
  const int*   labels = (const int*)d_in[2];
  const float* W1     = (const float*)d_in[3];
  const float* b1     = (const float*)d_in[4];
  const float* W2     = (const float*)d_in[5];
  const float* b2     = (const float*)d_in[6];
  float* out = (float*)d_out;

  char* ws = (char*)d_ws;
  size_t off = 0;
  auto alloc = [&](size_t bytes) -> void* {
    void* p = ws + off;
    off = (off + bytes + 255) & ~(size_t)255;
    return p;
  };
  u64*   keyS    = (u64*)  alloc((size_t)BF * NN * 8);
  int*   chunkOffG=(int*)  alloc((size_t)BF * 64 * 3 * 4);
  float* sboxes  = (float*)alloc((size_t)BF * NN * 7 * 4);
  float* sscore  = (float*)alloc((size_t)BF * NN * 4);
  float* slabel  = (float*)alloc((size_t)BF * NN * 4);
  int*   lab_slot= (int*)  alloc((size_t)BF * NN * 4);
  int*   loc_slot= (int*)  alloc((size_t)BF * NN * 4);
  int*   pglob   = (int*)  alloc((size_t)BF * 3 * PL * 4);
  float* px1     = (float*)alloc((size_t)BF * 3 * PL * 4);
  float* px2     = (float*)alloc((size_t)BF * 3 * PL * 4);
  float* py1     = (float*)alloc((size_t)BF * 3 * PL * 4);
  float* py2     = (float*)alloc((size_t)BF * 3 * PL * 4);
  float* parea   = (float*)alloc((size_t)BF * 3 * PL * 4);
  int*   VbufL   = (int*)  alloc((size_t)BF * 3 * 4);
  u64*   leadersP= (u64*)  alloc((size_t)BF * 3 * WL * 8);
  int*   cidP    = (int*)  alloc((size_t)BF * 3 * PL * 4);
  u64*   maskP   = (u64*)  alloc((size_t)BF * NN * WL * 8);        // 4 MB
  u64*   triT    = (u64*)  alloc((size_t)BF * 3 * TRI_CAP * 8);    // 3.2 MB
  (void)  alloc(32768);                     // DMA overrun slack after triT

  sort_kernel<<<BF, 1024, 0, stream>>>(scores, keyS);
  countscan_kernel<<<BF, 256, 0, stream>>>(keyS, labels, chunkOffG, VbufL);
  gather_kernel<<<BF * NN / 256, 256, 0, stream>>>(keyS, boxes, scores, labels,
                                                   chunkOffG, sboxes, sscore,
                                                   slabel, lab_slot, loc_slot,
                                                   pglob, px1, px2, py1, py2,
                                                   parea);
  mask_kernel<<<BF * 3 * 256, 256, 0, stream>>>(px1, px2, py1, py2, parea,
                                                pglob, VbufL, maskP, triT);
  nms_kernel<<<BF * 3, 64, 0, stream>>>(triT, VbufL, leadersP);
  cid_kernel<<<BF * NN / 4, 256, 0, stream>>>(maskP, leadersP, lab_slot,
                                              loc_slot, VbufL, cidP);
  mm_kernel<<<BF * NN, 64, 0, stream>>>(maskP, leadersP, cidP, lab_slot,
                                        loc_slot, pglob, VbufL, sboxes,
                                        sscore, slabel, W1, b1, W2, b2, out);
}

// Round 12
// 159.611 us; speedup vs baseline: 1.2552x; 1.0373x over previous
//
#include <hip/hip_runtime.h>
#include <stdint.h>

// Match numpy reference bit-exactly on the IoU path: no fma contraction.
#pragma clang fp contract(off)

#define BF 4
#define NN 4096
#define MAXC 16
#define PL 2048   // per-label partition capacity
#define WL 32     // PL/64 words per partition row
#define WF 24     // full-LDS leader-pass capacity (Vl<=1536; +15.7 sigma)
#define TRI_CAP (64 * (WL * (WL + 1) / 2))  // per-fl packed triangle capacity (u64)

typedef unsigned long long u64;
typedef uint32_t u32;

// Wave-local LDS sync: all LDS deps in mm are within one wave; drain DS queue
// and fence the compiler. (Old mm used __syncthreads in a 64-thr block, which
// was effectively this.)
#define WAVE_SYNC() asm volatile("s_waitcnt lgkmcnt(0)" ::: "memory")

__device__ __forceinline__ u64 shfl64(u64 v, int src) {
  return (u64)__shfl((long long)v, src, 64);
}
__device__ __forceinline__ u64 readlane64(u64 v, int l) {
  u32 lo = (u32)__builtin_amdgcn_readlane((int)(u32)v, l);
  u32 hi = (u32)__builtin_amdgcn_readlane((int)(u32)(v >> 32), l);
  return ((u64)hi << 32) | lo;
}
// Greedy NMS inside one 64-row block with ISO bulk-accept (R11, verified).
__device__ __forceinline__ u64 greedy64_iso(u64 D, u64 rem, u64 onlyme) {
  u64 lead = 0;
  while (rem) {
    u64 t = D & rem;
    u64 iso = __ballot(t == onlyme) & rem;  // bulk singleton leaders
    lead |= iso;
    rem &= ~iso;
    if (!rem) break;
    int b = __builtin_ctzll(rem);           // serial step 1 (multi-cluster)
    lead |= 1ull << b;
    rem &= ~readlane64(D, b);
    if (!rem) break;
    b = __builtin_ctzll(rem);               // serial step 2
    lead |= 1ull << b;
    rem &= ~readlane64(D, b);
  }
  return lead;
}

// ---------------------------------------------------------------------------
// K1 (R12): rank-based stable sort. rank(i) = #{j: key_j < key_i} over
// distinct u64 keys (idx tie-break) is exactly the stable argsort position.
// One block per 64 rows: stage all 4096 keys in LDS; wave w counts its
// 1024-j quarter via broadcast ds_read + v_cmp_lt_u64; sum 4 partials,
// scatter keyS[rank] = key. 256 blocks -> all CUs busy (vs radix on 4).
// ---------------------------------------------------------------------------
__global__ __launch_bounds__(256) void rank_kernel(
    const float* __restrict__ scores, u64* __restrict__ keyS)
{
  __shared__ u64 keys[NN];                  // 32 KB
  __shared__ int cnt[4][64];
  const int f = blockIdx.x >> 6, rb = blockIdx.x & 63;
  const int tid = threadIdx.x, wave = tid >> 6, lane = tid & 63;
  for (int s = 0; s < 16; s++) {
    int idx = tid + 256 * s;
    float sc = scores[f * NN + idx];
    bool valid = sc > 0.2f;                 // COND_THRES
    u32 bits = __float_as_uint(sc);
    u32 m = bits ^ ((bits >> 31) ? 0xFFFFFFFFu : 0x80000000u);
    u32 hi = valid ? ~m : 0xFFFFFFFFu;      // smaller = higher score
    keys[idx] = ((u64)hi << 32) | (u32)idx; // idx payload = stable tie-break
  }
  __syncthreads();
  const int row = rb * 64 + lane;
  const u64 mykey = keys[row];
  int c = 0;
  const int j0 = wave * 1024;
#pragma unroll 8
  for (int j = j0; j < j0 + 1024; j++)
    c += (keys[j] < mykey) ? 1 : 0;         // broadcast LDS read, pipelined
  cnt[wave][lane] = c;
  __syncthreads();
  if (wave == 0) {
    int rank = cnt[0][lane] + cnt[1][lane] + cnt[2][lane] + cnt[3][lane];
    keyS[f * NN + rank] = mykey;            // bijective scatter
  }
}

// ---------------------------------------------------------------------------
// K2: fused per-chunk label counts + exclusive scan (1 block/frame).
// ---------------------------------------------------------------------------
__global__ __launch_bounds__(256) void countscan_kernel(
    const u64* __restrict__ keyS, const int* __restrict__ labels,
    int* __restrict__ chunkOffG, int* __restrict__ VbufL)
{
  __shared__ int cnt[64][3];
  const int f = blockIdx.x, tid = threadIdx.x;
  const int wave = tid >> 6, lane = tid & 63;
  for (int s = 0; s < 16; s++) {
    int chunk = wave * 16 + s;
    int p = chunk * 64 + lane;
    u64 kv = keyS[f * NN + p];
    bool valid = (u32)(kv >> 32) != 0xFFFFFFFFu;
    int g = (int)(kv & 0xFFFFFFFFull);
    int l = valid ? labels[f * NN + g] : 3;
    u64 B0 = __ballot((l & 1) != 0);
    u64 B1 = __ballot((l & 2) != 0);
    if (lane < 3) {
      u64 Mb = ((lane & 1) ? B0 : ~B0) & ((lane & 2) ? B1 : ~B1);
      cnt[chunk][lane] = __popcll(Mb);
    }
  }
  __syncthreads();
  if (wave == 0) {
    for (int ll = 0; ll < 3; ll++) {
      int v = cnt[lane][ll];
      int incl = v;
      for (int off2 = 1; off2 < 64; off2 <<= 1) {
        int up = __shfl_up(incl, off2, 64);
        if (lane >= off2) incl += up;
      }
      chunkOffG[(f * 64 + lane) * 3 + ll] = incl - v;
      if (lane == 63) VbufL[f * 3 + ll] = incl;
    }
  }
}

// ---------------------------------------------------------------------------
// K3 (wide): gather sorted boxes/score/label + BEV + partition scatter.
// ---------------------------------------------------------------------------
__global__ __launch_bounds__(256) void gather_kernel(
    const u64* __restrict__ keyS, const float* __restrict__ boxes,
    const float* __restrict__ scores, const int* __restrict__ labels,
    const int* __restrict__ chunkOffG,
    float* __restrict__ sboxes, float* __restrict__ sscore, float* __restrict__ slabel,
    int* __restrict__ lab_slot, int* __restrict__ loc_slot,
    int* __restrict__ pglob,
    float* __restrict__ px1, float* __restrict__ px2, float* __restrict__ py1,
    float* __restrict__ py2, float* __restrict__ parea)
{
  const int gs = blockIdx.x * 256 + threadIdx.x;
  const int f = gs >> 12, p = gs & (NN - 1);
  const int lane = threadIdx.x & 63, chunk = p >> 6;
  const u64 ltmask = (1ull << lane) - 1ull;
  u64 kv = keyS[gs];
  bool valid = (u32)(kv >> 32) != 0xFFFFFFFFu;
  int g = (int)(kv & 0xFFFFFFFFull);
  const float* bp = boxes + (size_t)(f * NN + g) * 7;
  float b0 = bp[0], b1v = bp[1], b2v = bp[2], b3 = bp[3], b4 = bp[4], b5 = bp[5], b6 = bp[6];
  int lab = labels[f * NN + g];
  const int o = f * NN + p;
  float* sb = sboxes + (size_t)o * 7;
  sb[0] = b0; sb[1] = b1v; sb[2] = b2v; sb[3] = b3; sb[4] = b4; sb[5] = b5; sb[6] = b6;
  sscore[o] = scores[f * NN + g];
  slabel[o] = (float)lab;
  int l = valid ? lab : 3;
  u64 B0 = __ballot((l & 1) != 0);
  u64 B1 = __ballot((l & 2) != 0);
  u64 M = ((l & 1) ? B0 : ~B0) & ((l & 2) ? B1 : ~B1);
  int rank = __popcll(M & ltmask);
  if (l < 3) {
    int loc = chunkOffG[(f * 64 + chunk) * 3 + l] + rank;
    int pi = (f * 3 + l) * PL + loc;
    float off = (float)l * 10000.0f;        // CLASS_OFFSET
    float cx = b0 + off, cy = b1v;
    float hx = b3 * 0.5f, hy = b4 * 0.5f;
    float x1 = cx - hx, x2 = cx + hx, y1 = cy - hy, y2 = cy + hy;
    float area = (x2 - x1) * (y2 - y1);
    pglob[pi] = p;
    px1[pi] = x1; px2[pi] = x2; py1[pi] = y1; py2[pi] = y2; parea[pi] = area;
    lab_slot[o] = l; loc_slot[o] = loc;
  } else {
    lab_slot[o] = -1; loc_slot[o] = -1;
  }
}

// ---------------------------------------------------------------------------
// Kernel B: per-partition overlap bitmask, two layouts:
//   maskP[f][slot][w]  (row-major, for cid/mm)
//   triT [fl] packed lower-triangle: stream w at u64 offset
//             64*(w*W - w*(w-1)/2); contiguous per partition.
// ---------------------------------------------------------------------------
__global__ __launch_bounds__(256) void mask_kernel(
    const float* __restrict__ px1, const float* __restrict__ px2,
    const float* __restrict__ py1, const float* __restrict__ py2,
    const float* __restrict__ parea, const int* __restrict__ pglob,
    const int* __restrict__ VbufL,
    u64* __restrict__ maskP, u64* __restrict__ triT)
{
  __shared__ float4 cbox[1024];
  __shared__ float carea[1024];
  const int bx = blockIdx.x;                // fl*256 + rt*2 + wt
  const int fl = bx >> 8, rem = bx & 255;
  const int rt = rem >> 1, wt = rem & 1;
  const int r0 = rt * 16;
  const int Vl = VbufL[fl];
  if (r0 >= Vl) return;
  if (wt * 1024 >= Vl) return;
  const int tid = threadIdx.x;
  for (int q = tid; q < 1024; q += 256) {
    int c = fl * PL + wt * 1024 + q;
    cbox[q] = make_float4(px1[c], px2[c], py1[c], py2[c]);
    carea[q] = parea[c];
  }
  __syncthreads();
  const int row = r0 + (tid & 15);
  const int wl = tid >> 4;
  const int cw = wt * 16 + wl;
  const int nc = Vl - cw * 64;              // valid cols in this word
  if (row >= Vl || nc <= 0) return;
  const int rg = fl * PL + row;
  const float rx1 = px1[rg], rx2 = px2[rg], ry1 = py1[rg], ry2 = py2[rg], ra = parea[rg];
  u64 bits = 0;
  const int qb = wl * 64;
  for (int b = 0; b < 64; b++) {
    float4 cb = cbox[qb + b];
    float ca = carea[qb + b];
    float ix = fminf(rx2, cb.y) - fmaxf(rx1, cb.x);
    ix = fmaxf(ix, 0.0f);
    float iy = fminf(ry2, cb.w) - fmaxf(ry1, cb.z);
    iy = fmaxf(iy, 0.0f);
    float inter = ix * iy;
    float den = fmaxf((ra + ca) - inter, 1e-6f);
    float iou = inter / den;
    bits |= ((u64)(iou > 0.3f)) << b;       // IOU_THRES
  }
  if (nc < 64) bits &= (1ull << nc) - 1ull;
  const int f = fl / 3;
  const int p = pglob[fl * PL + row];
  maskP[((size_t)f * NN + p) * WL + cw] = bits;
  if (row >= 64 * cw) {                     // lower triangle only
    const int W = (Vl + 63) >> 6;
    int base = 64 * (cw * W - (cw * (cw - 1)) / 2);
    triT[(size_t)fl * TRI_CAP + base + (row - 64 * cw)] = bits;
  }
}

// ---------------------------------------------------------------------------
// Kernel C: leader pass (R11, verified). ONE WAVE per (frame,label).
// ---------------------------------------------------------------------------
__global__ __launch_bounds__(64) void nms_kernel(
    const u64* __restrict__ triT, const int* __restrict__ VbufL,
    u64* __restrict__ leadersP)
{
  __shared__ u64 tri[64 * (WF * (WF + 1) / 2) + 128];  // 153.6KB + 1KB slack
  const int fl = blockIdx.x, lane = threadIdx.x;
  const int Vl = VbufL[fl];
  const int W = (Vl + 63) >> 6;
  const u64* mT = triT + (size_t)fl * TRI_CAP;
  const u64 onlyme = 1ull << lane;
  u64 alive = 0;
  if (lane < WL) {
    int rb = Vl - 64 * lane;
    alive = (rb >= 64) ? ~0ull : ((rb > 0) ? ((1ull << rb) - 1ull) : 0ull);
  }
  u64 myLead = 0;

  if (W > 0 && W <= WF) {
    const int totw = 64 * (W * (W + 1) / 2);          // u64 count
    const int nch = (totw * 8 + 1023) >> 10;          // 1KB chunks
    const char* g = (const char*)mT;
    char* l = (char*)tri;
    int batch = 0;
    for (int it = 0; it < nch; it++) {
      __builtin_amdgcn_global_load_lds(
          (const __attribute__((address_space(1))) unsigned int*)(g + (size_t)it * 1024 + (size_t)lane * 16),
          (__attribute__((address_space(3))) unsigned int*)(l + (size_t)it * 1024),
          16, 0, 0);
      if (++batch == 48) {
        asm volatile("s_waitcnt vmcnt(0)" ::: "memory");
        batch = 0;
      }
    }
    asm volatile("s_waitcnt vmcnt(0)" ::: "memory");
    int offw = 0;
    u64 D = tri[lane];                      // diag of block 0
    for (int w = 0; w < W; w++) {
      const int offw_next = offw + 64 * (W - w);
      u64 Dnext = (w + 1 < W) ? tri[offw_next + lane] : 0;  // prefetch
      u64 lead = greedy64_iso(D, readlane64(alive, w), onlyme);
      if (lane == w) myLead = lead;
      if (lead) {
        const u64* strm = tri + offw;
        int v = w + 1;
        for (; v + 3 < W; v += 4) {
          u64 a0 = strm[64 * (v - w) + lane];
          u64 a1 = strm[64 * (v + 1 - w) + lane];
          u64 a2 = strm[64 * (v + 2 - w) + lane];
          u64 a3 = strm[64 * (v + 3 - w) + lane];
          u64 c0 = __ballot((a0 & lead) != 0ull);
          u64 c1 = __ballot((a1 & lead) != 0ull);
          u64 c2 = __ballot((a2 & lead) != 0ull);
          u64 c3 = __ballot((a3 & lead) != 0ull);
          if (lane == v)     alive &= ~c0;
          if (lane == v + 1) alive &= ~c1;
          if (lane == v + 2) alive &= ~c2;
          if (lane == v + 3) alive &= ~c3;
        }
        for (; v < W; v++) {
          u64 a0 = strm[64 * (v - w) + lane];
          u64 c0 = __ballot((a0 & lead) != 0ull);
          if (lane == v) alive &= ~c0;
        }
      }
      D = Dnext;
      offw = offw_next;
    }
  } else if (W > 0) {
    int offw = 0;
    for (int w = 0; w < W; w++) {
      const u64* strm = mT + offw;
      u64 D = strm[lane];
      u64 lead = greedy64_iso(D, readlane64(alive, w), onlyme);
      if (lane == w) myLead = lead;
      if (lead) {
        for (int v = w + 1; v < W; v++) {
          u64 a0 = strm[64 * (v - w) + lane];
          u64 c0 = __ballot((a0 & lead) != 0ull);
          if (lane == v) alive &= ~c0;
        }
      }
      offw += 64 * (W - w);
    }
  }
  if (lane < WL) leadersP[fl * WL + lane] = myLead;
}

// ---------------------------------------------------------------------------
// Kernel D: parallel cid (partition-local). One wave per slot.
// ---------------------------------------------------------------------------
__global__ __launch_bounds__(256) void cid_kernel(
    const u64* __restrict__ maskP, const u64* __restrict__ leadersP,
    const int* __restrict__ lab_slot, const int* __restrict__ loc_slot,
    const int* __restrict__ VbufL, int* __restrict__ cidP)
{
  const int g = blockIdx.x * 4 + (threadIdx.x >> 6);
  const int lane = threadIdx.x & 63;
  const int f = g >> 12, p = g & (NN - 1);
  const int l = lab_slot[f * NN + p];
  if (l < 0) return;
  const int fl = f * 3 + l;
  const int loc = loc_slot[f * NN + p];
  const int Wl = (VbufL[fl] + 63) >> 6;
  u64 L = 0, m = 0;
  if (lane < Wl) {
    L = leadersP[fl * WL + lane];
    m = maskP[((size_t)f * NN + p) * WL + lane];
  }
  const int g6 = loc >> 6, b6 = loc & 63;
  u64 pmask = (lane < g6) ? ~0ull
            : (lane == g6 ? ((b6 == 63) ? ~0ull : ((1ull << (b6 + 1)) - 1ull)) : 0ull);
  u64 v = m & L & pmask;
  u64 bl = __ballot(v != 0ull);
  int cid = -1;
  if (bl != 0ull) {
    int w = __builtin_ctzll(bl);
    u64 vw = shfl64(v, w);
    cid = w * 64 + __builtin_ctzll(vw);
  }
  if (lane == 0) cidP[fl * PL + loc] = cid;
}

// ---------------------------------------------------------------------------
// Kernel E (R12): fused members + merge, 4 waves/block (4096 blocks instead
// of 16384). All LDS deps are wave-local (per-wave slices) -> WAVE_SYNC()
// replaces __syncthreads(); per-wave early-out is safe (no block barriers).
// ---------------------------------------------------------------------------
__global__ __launch_bounds__(256) void mm_kernel(
    const u64* __restrict__ maskP, const u64* __restrict__ leadersP,
    const int* __restrict__ cidP, const int* __restrict__ lab_slot,
    const int* __restrict__ loc_slot, const int* __restrict__ pglob,
    const int* __restrict__ VbufL,
    const float* __restrict__ sboxes, const float* __restrict__ sscore,
    const float* __restrict__ slabel,
    const float* __restrict__ W1, const float* __restrict__ b1,
    const float* __restrict__ W2, const float* __restrict__ b2,
    float* __restrict__ out)
{
  __shared__ int   mlistS[4][MAXC];
  __shared__ float mbS[4][MAXC][7];
  __shared__ float lgS[4][MAXC];
  __shared__ float wnS[4][MAXC];
  const int wv = threadIdx.x >> 6, lane = threadIdx.x & 63;
  const int bi = blockIdx.x * 4 + wv;
  const int f = bi >> 12, i = bi & (NN - 1);
  const int o = f * NN + i;
  float* info = out + (size_t)o * 9;
  float* lead = out + (size_t)BF * NN * 9 + o;
  const int l = lab_slot[o];
  bool isLead = false;
  int loc = 0, fl = 0;
  if (l >= 0) {
    fl = f * 3 + l;
    loc = loc_slot[o];
    isLead = (leadersP[fl * WL + (loc >> 6)] >> (loc & 63)) & 1ull;
  }
  if (!isLead) {
    if (lane < 9) info[lane] = 0.0f;
    if (lane == 0) *lead = 0.0f;
    return;                                 // per-wave: no block barriers
  }
  int* mlist = mlistS[wv];
  float (*mb)[7] = mbS[wv];
  float* lg = lgS[wv];
  float* wn = wnS[wv];
  const u64* mrow = maskP + (size_t)o * WL;
  const int Wl = (VbufL[fl] + 63) >> 6;
  int total = 0;
  for (int w = loc >> 6; w < Wl && total < MAXC; w++) {
    u64 word = mrow[w];
    int pos = w * 64 + lane;
    bool cand = ((word >> lane) & 1ull) && (cidP[fl * PL + pos] == loc);
    u64 mbal = __ballot(cand);
    int r = __popcll(mbal & ((1ull << lane) - 1ull));
    int slot = total + r;
    if (cand && slot < MAXC) mlist[slot] = pglob[fl * PL + pos];
    total += __popcll(mbal);
  }
  const int cnt = min(total, MAXC);
  WAVE_SYNC();
  if (lane < cnt) {
    int j = mlist[lane];
    const float* bp = sboxes + (size_t)(f * NN + j) * 7;
    for (int d = 0; d < 7; d++) mb[lane][d] = bp[d];
  }
  float w1r[7];
  for (int d = 0; d < 7; d++) w1r[d] = W1[d * 64 + lane];
  const float b1c = b1[lane], w2c = W2[lane], b2v = b2[0];
  WAVE_SYNC();
  for (int s = 0; s < cnt; s++) {
    float t = b1c;
    for (int d = 0; d < 7; d++) t += mb[s][d] * w1r[d];
    float h = fmaxf(t, 0.0f);
    float v = h * w2c;
    for (int off2 = 32; off2 > 0; off2 >>= 1) v += __shfl_xor(v, off2, 64);
    if (lane == 0) lg[s] = v + b2v;
  }
  WAVE_SYNC();
  float mx = -1e30f;
  for (int s = 0; s < cnt; s++) mx = fmaxf(mx, lg[s]);
  float den = 0.0f;
  for (int s = 0; s < cnt; s++) den += expf(lg[s] - mx);
  if (lane < cnt) wn[lane] = expf(lg[lane] - mx) / den;
  WAVE_SYNC();
  float val = 0.0f;
  if (lane < 7) {
    float acc = 0.0f;
    for (int s = 0; s < cnt; s++) acc += wn[s] * mb[s][lane];
    val = acc;
    if (lane >= 3 && lane <= 5 && val <= 0.0f) val = sboxes[(size_t)o * 7 + lane];
  } else if (lane == 7) {
    val = sscore[o];
  } else if (lane == 8) {
    val = slabel[o];
  }
  if (lane < 9) info[lane] = val;
  if (lane == 0) *lead = 1.0f;
}

// ---------------------------------------------------------------------------
extern "C" void kernel_launch(void* const* d_in, const int* in_sizes, int n_in,
                              void* d_out, int out_size, void* d_ws, size_t ws_size,
                              hipStream_t stream)
{
  const float* boxes  = (const float*)d_in[0];
  const float* scores = (const float*)d_in[1];
  const int*   labels = (const int*)d_in[2];
  const float* W1     = (const float*)d_in[3];
  const float* b1     = (const float*)d_in[4];
  const float* W2     = (const float*)d_in[5];
  const float* b2     = (const float*)d_in[6];
  float* out = (float*)d_out;

  char* ws = (char*)d_ws;
  size_t off = 0;
  auto alloc = [&](size_t bytes) -> void* {
    void* p = ws + off;
    off = (off + bytes + 255) & ~(size_t)255;
    return p;
  };
  u64*   keyS    = (u64*)  alloc((size_t)BF * NN * 8);
  int*   chunkOffG=(int*)  alloc((size_t)BF * 64 * 3 * 4);
  float* sboxes  = (float*)alloc((size_t)BF * NN * 7 * 4);
  float* sscore  = (float*)alloc((size_t)BF * NN * 4);
  float* slabel  = (float*)alloc((size_t)BF * NN * 4);
  int*   lab_slot= (int*)  alloc((size_t)BF * NN * 4);
  int*   loc_slot= (int*)  alloc((size_t)BF * NN * 4);
  int*   pglob   = (int*)  alloc((size_t)BF * 3 * PL * 4);
  float* px1     = (float*)alloc((size_t)BF * 3 * PL * 4);
  float* px2     = (float*)alloc((size_t)BF * 3 * PL * 4);
  float* py1     = (float*)alloc((size_t)BF * 3 * PL * 4);
  float* py2     = (float*)alloc((size_t)BF * 3 * PL * 4);
  float* parea   = (float*)alloc((size_t)BF * 3 * PL * 4);
  int*   VbufL   = (int*)  alloc((size_t)BF * 3 * 4);
  u64*   leadersP= (u64*)  alloc((size_t)BF * 3 * WL * 8);
  int*   cidP    = (int*)  alloc((size_t)BF * 3 * PL * 4);
  u64*   maskP   = (u64*)  alloc((size_t)BF * NN * WL * 8);        // 4 MB
  u64*   triT    = (u64*)  alloc((size_t)BF * 3 * TRI_CAP * 8);    // 3.2 MB
  (void)  alloc(32768);                     // DMA overrun slack after triT

  rank_kernel<<<BF * 64, 256, 0, stream>>>(scores, keyS);
  countscan_kernel<<<BF, 256, 0, stream>>>(keyS, labels, chunkOffG, VbufL);
  gather_kernel<<<BF * NN / 256, 256, 0, stream>>>(keyS, boxes, scores, labels,
                                                   chunkOffG, sboxes, sscore,
                                                   slabel, lab_slot, loc_slot,
                                                   pglob, px1, px2, py1, py2,
                                                   parea);
  mask_kernel<<<BF * 3 * 256, 256, 0, stream>>>(px1, px2, py1, py2, parea,
                                                pglob, VbufL, maskP, triT);
  nms_kernel<<<BF * 3, 64, 0, stream>>>(triT, VbufL, leadersP);
  cid_kernel<<<BF * NN / 4, 256, 0, stream>>>(maskP, leadersP, lab_slot,
                                              loc_slot, VbufL, cidP);
  mm_kernel<<<BF * NN / 4, 256, 0, stream>>>(maskP, leadersP, cidP, lab_slot,
                                             loc_slot, pglob, VbufL, sboxes,
                                             sscore, slabel, W1, b1, W2, b2, out);
}

// Round 13
// 156.810 us; speedup vs baseline: 1.2776x; 1.0179x over previous
//
#include <hip/hip_runtime.h>
#include <stdint.h>

// Match numpy reference bit-exactly on the IoU path: no fma contraction.
#pragma clang fp contract(off)

#define BF 4
#define NN 4096
#define MAXC 16
#define PL 2048   // per-label partition capacity
#define WL 32     // PL/64 words per partition row
#define WF 24     // full-LDS leader-pass capacity (Vl<=1536; +15.7 sigma)
#define TRI_CAP (64 * (WL * (WL + 1) / 2))  // per-fl packed triangle capacity (u64)

typedef unsigned long long u64;
typedef uint32_t u32;

// Wave-local LDS sync (mm: all LDS deps are within one wave).
#define WAVE_SYNC() asm volatile("s_waitcnt lgkmcnt(0)" ::: "memory")

__device__ __forceinline__ u64 shfl64(u64 v, int src) {
  return (u64)__shfl((long long)v, src, 64);
}
__device__ __forceinline__ u64 readlane64(u64 v, int l) {
  u32 lo = (u32)__builtin_amdgcn_readlane((int)(u32)v, l);
  u32 hi = (u32)__builtin_amdgcn_readlane((int)(u32)(v >> 32), l);
  return ((u64)hi << 32) | lo;
}
// Greedy NMS inside one 64-row block with ISO bulk-accept (R11, verified).
__device__ __forceinline__ u64 greedy64_iso(u64 D, u64 rem, u64 onlyme) {
  u64 lead = 0;
  while (rem) {
    u64 t = D & rem;
    u64 iso = __ballot(t == onlyme) & rem;  // bulk singleton leaders
    lead |= iso;
    rem &= ~iso;
    if (!rem) break;
    int b = __builtin_ctzll(rem);           // serial step 1 (multi-cluster)
    lead |= 1ull << b;
    rem &= ~readlane64(D, b);
    if (!rem) break;
    b = __builtin_ctzll(rem);               // serial step 2
    lead |= 1ull << b;
    rem &= ~readlane64(D, b);
  }
  return lead;
}

// ---------------------------------------------------------------------------
// K1 (R13): fused rank + partition-loc + gather/scatter. Key trick: pack the
// label into the key's LOW bits: lo32 = (idx<<2) | (valid?lab:3). Keys stay
// distinct; tie-break stays pure idx (idx above lab bits). Then ONE pairwise
// pass yields rank = #{key_j<key_i} (stable argsort position) AND
// loc = #{key_j<key_i && lab_j==lab_i} (position inside the label partition
// = old countscan+ballot value). Block rb==0 also reduces VbufL. Wave 0's
// tail does the whole gather+BEV+partition scatter (old gather_kernel).
// Removes countscan_kernel, gather_kernel, keyS, chunkOffG.
// ---------------------------------------------------------------------------
__global__ __launch_bounds__(256) void rg_kernel(
    const float* __restrict__ scores, const float* __restrict__ boxes,
    const int* __restrict__ labels,
    float* __restrict__ sboxes, float* __restrict__ sscore, float* __restrict__ slabel,
    int* __restrict__ lab_slot, int* __restrict__ loc_slot,
    int* __restrict__ pglob,
    float* __restrict__ px1, float* __restrict__ px2, float* __restrict__ py1,
    float* __restrict__ py2, float* __restrict__ parea,
    int* __restrict__ VbufL)
{
  __shared__ u64 keys[NN];                  // 32 KB
  __shared__ int cnt[4][64];
  __shared__ int lcnt[4][64];
  __shared__ int vc[4][3];
  const int f = blockIdx.x >> 6, rb = blockIdx.x & 63;
  const int tid = threadIdx.x, wave = tid >> 6, lane = tid & 63;
  for (int s = 0; s < 16; s++) {
    int idx = tid + 256 * s;
    float sc = scores[f * NN + idx];
    bool valid = sc > 0.2f;                 // COND_THRES
    int lab = labels[f * NN + idx];
    u32 bits = __float_as_uint(sc);
    u32 m = bits ^ ((bits >> 31) ? 0xFFFFFFFFu : 0x80000000u);
    u32 hi = valid ? ~m : 0xFFFFFFFFu;      // smaller = higher score
    u32 lo = ((u32)idx << 2) | (valid ? (u32)lab : 3u);
    keys[idx] = ((u64)hi << 32) | lo;
  }
  __syncthreads();
  // per-label totals (block rb==0 only), concurrent with rank counting
  if (rb == 0) {
    int c0 = 0, c1 = 0, c2 = 0;
    const int base = wave * 1024;
    for (int s = 0; s < 16; s++) {
      u32 lb = (u32)keys[base + s * 64 + lane] & 3u;
      c0 += (lb == 0); c1 += (lb == 1); c2 += (lb == 2);
    }
    for (int off = 32; off; off >>= 1) {
      c0 += __shfl_xor(c0, off, 64);
      c1 += __shfl_xor(c1, off, 64);
      c2 += __shfl_xor(c2, off, 64);
    }
    if (lane == 0) { vc[wave][0] = c0; vc[wave][1] = c1; vc[wave][2] = c2; }
  }
  // rank + loc quarter counts: wave w scans j in [w*1024,(w+1)*1024)
  const int row = rb * 64 + lane;
  const u64 mykey = keys[row];
  const u32 mylab = (u32)mykey & 3u;
  int c = 0, lc = 0;
  const int j0 = wave * 1024;
#pragma unroll 8
  for (int j = j0; j < j0 + 1024; j++) {
    u64 kj = keys[j];                       // broadcast LDS read
    bool lt = kj < mykey;
    c += lt ? 1 : 0;
    lc += (lt && (((u32)kj & 3u) == mylab)) ? 1 : 0;
  }
  cnt[wave][lane] = c;
  lcnt[wave][lane] = lc;
  __syncthreads();
  if (rb == 0 && wave == 1 && lane < 3)
    VbufL[f * 3 + lane] = vc[0][lane] + vc[1][lane] + vc[2][lane] + vc[3][lane];
  if (wave == 0) {                          // tail: gather + scatter, 1 row/lane
    int rank = cnt[0][lane] + cnt[1][lane] + cnt[2][lane] + cnt[3][lane];
    int loc  = lcnt[0][lane] + lcnt[1][lane] + lcnt[2][lane] + lcnt[3][lane];
    const int i = row;                      // original index
    const float* bp = boxes + (size_t)(f * NN + i) * 7;
    float b0 = bp[0], b1v = bp[1], b2v = bp[2], b3 = bp[3], b4 = bp[4], b5 = bp[5], b6 = bp[6];
    int lab = labels[f * NN + i];
    float sc = scores[f * NN + i];
    const int o = f * NN + rank;
    float* sb = sboxes + (size_t)o * 7;
    sb[0] = b0; sb[1] = b1v; sb[2] = b2v; sb[3] = b3; sb[4] = b4; sb[5] = b5; sb[6] = b6;
    sscore[o] = sc;
    slabel[o] = (float)lab;
    if (mylab < 3u) {                       // valid: mylab == lab
      int pi = (f * 3 + (int)mylab) * PL + loc;
      float off = (float)mylab * 10000.0f;  // CLASS_OFFSET
      float cx = b0 + off, cy = b1v;
      float hx = b3 * 0.5f, hy = b4 * 0.5f;
      float x1 = cx - hx, x2 = cx + hx, y1 = cy - hy, y2 = cy + hy;
      float area = (x2 - x1) * (y2 - y1);
      pglob[pi] = rank;
      px1[pi] = x1; px2[pi] = x2; py1[pi] = y1; py2[pi] = y2; parea[pi] = area;
      lab_slot[o] = (int)mylab; loc_slot[o] = loc;
    } else {
      lab_slot[o] = -1; loc_slot[o] = -1;
    }
  }
}

// ---------------------------------------------------------------------------
// Kernel B: per-partition overlap bitmask, two layouts. R13: stage only the
// valid columns (ncol) — garbage LDS beyond ncol is read only for bit
// positions masked out by nc (provably harmless).
// ---------------------------------------------------------------------------
__global__ __launch_bounds__(256) void mask_kernel(
    const float* __restrict__ px1, const float* __restrict__ px2,
    const float* __restrict__ py1, const float* __restrict__ py2,
    const float* __restrict__ parea, const int* __restrict__ pglob,
    const int* __restrict__ VbufL,
    u64* __restrict__ maskP, u64* __restrict__ triT)
{
  __shared__ float4 cbox[1024];
  __shared__ float carea[1024];
  const int bx = blockIdx.x;                // fl*256 + rt*2 + wt
  const int fl = bx >> 8, rem = bx & 255;
  const int rt = rem >> 1, wt = rem & 1;
  const int r0 = rt * 16;
  const int Vl = VbufL[fl];
  if (r0 >= Vl) return;
  if (wt * 1024 >= Vl) return;
  const int tid = threadIdx.x;
  const int ncol = Vl - wt * 1024;
  const int nload = (ncol < 1024) ? ncol : 1024;
  for (int q = tid; q < nload; q += 256) {
    int c = fl * PL + wt * 1024 + q;
    cbox[q] = make_float4(px1[c], px2[c], py1[c], py2[c]);
    carea[q] = parea[c];
  }
  __syncthreads();
  const int row = r0 + (tid & 15);
  const int wl = tid >> 4;
  const int cw = wt * 16 + wl;
  const int nc = Vl - cw * 64;              // valid cols in this word
  if (row >= Vl || nc <= 0) return;
  const int rg = fl * PL + row;
  const float rx1 = px1[rg], rx2 = px2[rg], ry1 = py1[rg], ry2 = py2[rg], ra = parea[rg];
  u64 bits = 0;
  const int qb = wl * 64;
  for (int b = 0; b < 64; b++) {
    float4 cb = cbox[qb + b];
    float ca = carea[qb + b];
    float ix = fminf(rx2, cb.y) - fmaxf(rx1, cb.x);
    ix = fmaxf(ix, 0.0f);
    float iy = fminf(ry2, cb.w) - fmaxf(ry1, cb.z);
    iy = fmaxf(iy, 0.0f);
    float inter = ix * iy;
    float den = fmaxf((ra + ca) - inter, 1e-6f);
    float iou = inter / den;
    bits |= ((u64)(iou > 0.3f)) << b;       // IOU_THRES
  }
  if (nc < 64) bits &= (1ull << nc) - 1ull;
  const int f = fl / 3;
  const int p = pglob[fl * PL + row];
  maskP[((size_t)f * NN + p) * WL + cw] = bits;
  if (row >= 64 * cw) {                     // lower triangle only
    const int W = (Vl + 63) >> 6;
    int base = 64 * (cw * W - (cw * (cw - 1)) / 2);
    triT[(size_t)fl * TRI_CAP + base + (row - 64 * cw)] = bits;
  }
}

// ---------------------------------------------------------------------------
// Kernel C: leader pass (R11, verified). ONE WAVE per (frame,label).
// ---------------------------------------------------------------------------
__global__ __launch_bounds__(64) void nms_kernel(
    const u64* __restrict__ triT, const int* __restrict__ VbufL,
    u64* __restrict__ leadersP)
{
  __shared__ u64 tri[64 * (WF * (WF + 1) / 2) + 128];  // 153.6KB + 1KB slack
  const int fl = blockIdx.x, lane = threadIdx.x;
  const int Vl = VbufL[fl];
  const int W = (Vl + 63) >> 6;
  const u64* mT = triT + (size_t)fl * TRI_CAP;
  const u64 onlyme = 1ull << lane;
  u64 alive = 0;
  if (lane < WL) {
    int rb = Vl - 64 * lane;
    alive = (rb >= 64) ? ~0ull : ((rb > 0) ? ((1ull << rb) - 1ull) : 0ull);
  }
  u64 myLead = 0;

  if (W > 0 && W <= WF) {
    const int totw = 64 * (W * (W + 1) / 2);          // u64 count
    const int nch = (totw * 8 + 1023) >> 10;          // 1KB chunks
    const char* g = (const char*)mT;
    char* l = (char*)tri;
    int batch = 0;
    for (int it = 0; it < nch; it++) {
      __builtin_amdgcn_global_load_lds(
          (const __attribute__((address_space(1))) unsigned int*)(g + (size_t)it * 1024 + (size_t)lane * 16),
          (__attribute__((address_space(3))) unsigned int*)(l + (size_t)it * 1024),
          16, 0, 0);
      if (++batch == 48) {
        asm volatile("s_waitcnt vmcnt(0)" ::: "memory");
        batch = 0;
      }
    }
    asm volatile("s_waitcnt vmcnt(0)" ::: "memory");
    int offw = 0;
    u64 D = tri[lane];                      // diag of block 0
    for (int w = 0; w < W; w++) {
      const int offw_next = offw + 64 * (W - w);
      u64 Dnext = (w + 1 < W) ? tri[offw_next + lane] : 0;  // prefetch
      u64 lead = greedy64_iso(D, readlane64(alive, w), onlyme);
      if (lane == w) myLead = lead;
      if (lead) {
        const u64* strm = tri + offw;
        int v = w + 1;
        for (; v + 3 < W; v += 4) {
          u64 a0 = strm[64 * (v - w) + lane];
          u64 a1 = strm[64 * (v + 1 - w) + lane];
          u64 a2 = strm[64 * (v + 2 - w) + lane];
          u64 a3 = strm[64 * (v + 3 - w) + lane];
          u64 c0 = __ballot((a0 & lead) != 0ull);
          u64 c1 = __ballot((a1 & lead) != 0ull);
          u64 c2 = __ballot((a2 & lead) != 0ull);
          u64 c3 = __ballot((a3 & lead) != 0ull);
          if (lane == v)     alive &= ~c0;
          if (lane == v + 1) alive &= ~c1;
          if (lane == v + 2) alive &= ~c2;
          if (lane == v + 3) alive &= ~c3;
        }
        for (; v < W; v++) {
          u64 a0 = strm[64 * (v - w) + lane];
          u64 c0 = __ballot((a0 & lead) != 0ull);
          if (lane == v) alive &= ~c0;
        }
      }
      D = Dnext;
      offw = offw_next;
    }
  } else if (W > 0) {
    int offw = 0;
    for (int w = 0; w < W; w++) {
      const u64* strm = mT + offw;
      u64 D = strm[lane];
      u64 lead = greedy64_iso(D, readlane64(alive, w), onlyme);
      if (lane == w) myLead = lead;
      if (lead) {
        for (int v = w + 1; v < W; v++) {
          u64 a0 = strm[64 * (v - w) + lane];
          u64 c0 = __ballot((a0 & lead) != 0ull);
          if (lane == v) alive &= ~c0;
        }
      }
      offw += 64 * (W - w);
    }
  }
  if (lane < WL) leadersP[fl * WL + lane] = myLead;
}

// ---------------------------------------------------------------------------
// Kernel D: parallel cid (partition-local). One wave per slot.
// ---------------------------------------------------------------------------
__global__ __launch_bounds__(256) void cid_kernel(
    const u64* __restrict__ maskP, const u64* __restrict__ leadersP,
    const int* __restrict__ lab_slot, const int* __restrict__ loc_slot,
    const int* __restrict__ VbufL, int* __restrict__ cidP)
{
  const int g = blockIdx.x * 4 + (threadIdx.x >> 6);
  const int lane = threadIdx.x & 63;
  const int f = g >> 12, p = g & (NN - 1);
  const int l = lab_slot[f * NN + p];
  if (l < 0) return;
  const int fl = f * 3 + l;
  const int loc = loc_slot[f * NN + p];
  const int Wl = (VbufL[fl] + 63) >> 6;
  u64 L = 0, m = 0;
  if (lane < Wl) {
    L = leadersP[fl * WL + lane];
    m = maskP[((size_t)f * NN + p) * WL + lane];
  }
  const int g6 = loc >> 6, b6 = loc & 63;
  u64 pmask = (lane < g6) ? ~0ull
            : (lane == g6 ? ((b6 == 63) ? ~0ull : ((1ull << (b6 + 1)) - 1ull)) : 0ull);
  u64 v = m & L & pmask;
  u64 bl = __ballot(v != 0ull);
  int cid = -1;
  if (bl != 0ull) {
    int w = __builtin_ctzll(bl);
    u64 vw = shfl64(v, w);
    cid = w * 64 + __builtin_ctzll(vw);
  }
  if (lane == 0) cidP[fl * PL + loc] = cid;
}

// ---------------------------------------------------------------------------
// Kernel E: fused members + merge, 4 waves/block (R12, verified).
// ---------------------------------------------------------------------------
__global__ __launch_bounds__(256) void mm_kernel(
    const u64* __restrict__ maskP, const u64* __restrict__ leadersP,
    const int* __restrict__ cidP, const int* __restrict__ lab_slot,
    const int* __restrict__ loc_slot, const int* __restrict__ pglob,
    const int* __restrict__ VbufL,
    const float* __restrict__ sboxes, const float* __restrict__ sscore,
    const float* __restrict__ slabel,
    const float* __restrict__ W1, const float* __restrict__ b1,
    const float* __restrict__ W2, const float* __restrict__ b2,
    float* __restrict__ out)
{
  __shared__ int   mlistS[4][MAXC];
  __shared__ float mbS[4][MAXC][7];
  __shared__ float lgS[4][MAXC];
  __shared__ float wnS[4][MAXC];
  const int wv = threadIdx.x >> 6, lane = threadIdx.x & 63;
  const int bi = blockIdx.x * 4 + wv;
  const int f = bi >> 12, i = bi & (NN - 1);
  const int o = f * NN + i;
  float* info = out + (size_t)o * 9;
  float* lead = out + (size_t)BF * NN * 9 + o;
  const int l = lab_slot[o];
  bool isLead = false;
  int loc = 0, fl = 0;
  if (l >= 0) {
    fl = f * 3 + l;
    loc = loc_slot[o];
    isLead = (leadersP[fl * WL + (loc >> 6)] >> (loc & 63)) & 1ull;
  }
  if (!isLead) {
    if (lane < 9) info[lane] = 0.0f;
    if (lane == 0) *lead = 0.0f;
    return;                                 // per-wave: no block barriers
  }
  int* mlist = mlistS[wv];
  float (*mb)[7] = mbS[wv];
  float* lg = lgS[wv];
  float* wn = wnS[wv];
  const u64* mrow = maskP + (size_t)o * WL;
  const int Wl = (VbufL[fl] + 63) >> 6;
  int total = 0;
  for (int w = loc >> 6; w < Wl && total < MAXC; w++) {
    u64 word = mrow[w];
    int pos = w * 64 + lane;
    bool cand = ((word >> lane) & 1ull) && (cidP[fl * PL + pos] == loc);
    u64 mbal = __ballot(cand);
    int r = __popcll(mbal & ((1ull << lane) - 1ull));
    int slot = total + r;
    if (cand && slot < MAXC) mlist[slot] = pglob[fl * PL + pos];
    total += __popcll(mbal);
  }
  const int cnt = min(total, MAXC);
  WAVE_SYNC();
  if (lane < cnt) {
    int j = mlist[lane];
    const float* bp = sboxes + (size_t)(f * NN + j) * 7;
    for (int d = 0; d < 7; d++) mb[lane][d] = bp[d];
  }
  float w1r[7];
  for (int d = 0; d < 7; d++) w1r[d] = W1[d * 64 + lane];
  const float b1c = b1[lane], w2c = W2[lane], b2v = b2[0];
  WAVE_SYNC();
  for (int s = 0; s < cnt; s++) {
    float t = b1c;
    for (int d = 0; d < 7; d++) t += mb[s][d] * w1r[d];
    float h = fmaxf(t, 0.0f);
    float v = h * w2c;
    for (int off2 = 32; off2 > 0; off2 >>= 1) v += __shfl_xor(v, off2, 64);
    if (lane == 0) lg[s] = v + b2v;
  }
  WAVE_SYNC();
  float mx = -1e30f;
  for (int s = 0; s < cnt; s++) mx = fmaxf(mx, lg[s]);
  float den = 0.0f;
  for (int s = 0; s < cnt; s++) den += expf(lg[s] - mx);
  if (lane < cnt) wn[lane] = expf(lg[lane] - mx) / den;
  WAVE_SYNC();
  float val = 0.0f;
  if (lane < 7) {
    float acc = 0.0f;
    for (int s = 0; s < cnt; s++) acc += wn[s] * mb[s][lane];
    val = acc;
    if (lane >= 3 && lane <= 5 && val <= 0.0f) val = sboxes[(size_t)o * 7 + lane];
  } else if (lane == 7) {
    val = sscore[o];
  } else if (lane == 8) {
    val = slabel[o];
  }
  if (lane < 9) info[lane] = val;
  if (lane == 0) *lead = 1.0f;
}

// ---------------------------------------------------------------------------
extern "C" void kernel_launch(void* const* d_in, const int* in_sizes, int n_in,
                              void* d_out, int out_size, void* d_ws, size_t ws_size,
                              hipStream_t stream)
{
  const float* boxes  = (const float*)d_in[0];
  const float* scores = (const float*)d_in[1];
  const int*   labels = (const int*)d_in[2];
  const float* W1     = (const float*)d_in[3];
  const float* b1     = (const float*)d_in[4];
  const float* W2     = (const float*)d_in[5];
  const float* b2     = (const float*)d_in[6];
  float* out = (float*)d_out;

  char* ws = (char*)d_ws;
  size_t off = 0;
  auto alloc = [&](size_t bytes) -> void* {
    void* p = ws + off;
    off = (off + bytes + 255) & ~(size_t)255;
    return p;
  };
  float* sboxes  = (float*)alloc((size_t)BF * NN * 7 * 4);
  float* sscore  = (float*)alloc((size_t)BF * NN * 4);
  float* slabel  = (float*)alloc((size_t)BF * NN * 4);
  int*   lab_slot= (int*)  alloc((size_t)BF * NN * 4);
  int*   loc_slot= (int*)  alloc((size_t)BF * NN * 4);
  int*   pglob   = (int*)  alloc((size_t)BF * 3 * PL * 4);
  float* px1     = (float*)alloc((size_t)BF * 3 * PL * 4);
  float* px2     = (float*)alloc((size_t)BF * 3 * PL * 4);
  float* py1     = (float*)alloc((size_t)BF * 3 * PL * 4);
  float* py2     = (float*)alloc((size_t)BF * 3 * PL * 4);
  float* parea   = (float*)alloc((size_t)BF * 3 * PL * 4);
  int*   VbufL   = (int*)  alloc((size_t)BF * 3 * 4);
  u64*   leadersP= (u64*)  alloc((size_t)BF * 3 * WL * 8);
  int*   cidP    = (int*)  alloc((size_t)BF * 3 * PL * 4);
  u64*   maskP   = (u64*)  alloc((size_t)BF * NN * WL * 8);        // 4 MB
  u64*   triT    = (u64*)  alloc((size_t)BF * 3 * TRI_CAP * 8);    // 3.2 MB
  (void)  alloc(32768);                     // DMA overrun slack after triT

  rg_kernel<<<BF * 64, 256, 0, stream>>>(scores, boxes, labels, sboxes,
                                         sscore, slabel, lab_slot, loc_slot,
                                         pglob, px1, px2, py1, py2, parea,
                                         VbufL);
  mask_kernel<<<BF * 3 * 256, 256, 0, stream>>>(px1, px2, py1, py2, parea,
                                                pglob, VbufL, maskP, triT);
  nms_kernel<<<BF * 3, 64, 0, stream>>>(triT, VbufL, leadersP);
  cid_kernel<<<BF * NN / 4, 256, 0, stream>>>(maskP, leadersP, lab_slot,
                                              loc_slot, VbufL, cidP);
  mm_kernel<<<BF * NN / 4, 256, 0, stream>>>(maskP, leadersP, cidP, lab_slot,
                                             loc_slot, pglob, VbufL, sboxes,
                                             sscore, slabel, W1, b1, W2, b2, out);
}